// Round 11
// baseline (366.921 us; speedup 1.0000x reference)
//
#include <hip/hip_runtime.h>
#include <hip/hip_bf16.h>
#include <hip/hip_fp16.h>

// ---------------- degree histogram, 4 edges/thread ----------------
__global__ __launch_bounds__(256) void deg4(const int* __restrict__ dst,
                                            int* __restrict__ cnt, int E) {
    int base = blockIdx.x * 1024 + threadIdx.x * 4;
    if (base + 3 < E) {
        int d0 = dst[base], d1 = dst[base + 1], d2 = dst[base + 2], d3 = dst[base + 3];
        atomicAdd(&cnt[d0], 1); atomicAdd(&cnt[d1], 1);
        atomicAdd(&cnt[d2], 1); atomicAdd(&cnt[d3], 1);
    } else {
        for (int e = base; e < E; ++e) atomicAdd(&cnt[dst[e]], 1);
    }
}

// ---------------- hierarchical exclusive scan of (cnt[i]+1) -> rowptr ----------------
__global__ void scan1(const int* __restrict__ cnt, int* __restrict__ tmp,
                      int* __restrict__ bsum, int n) {
    __shared__ int s[256];
    int i = blockIdx.x * 256 + threadIdx.x;
    int v = (i < n) ? (cnt[i] + 1) : 0;
    s[threadIdx.x] = v;
    __syncthreads();
    for (int off = 1; off < 256; off <<= 1) {
        int x = (threadIdx.x >= off) ? s[threadIdx.x - off] : 0;
        __syncthreads();
        s[threadIdx.x] += x;
        __syncthreads();
    }
    if (i < n) tmp[i] = s[threadIdx.x];
    if (threadIdx.x == 255) bsum[blockIdx.x] = s[255];
}

__global__ void scan2(int* bsum, int nb) {
    __shared__ int s[256];
    int t = threadIdx.x;
    int v = (t < nb) ? bsum[t] : 0;
    s[t] = v;
    __syncthreads();
    for (int off = 1; off < 256; off <<= 1) {
        int x = (t >= off) ? s[t - off] : 0;
        __syncthreads();
        s[t] += x;
        __syncthreads();
    }
    if (t < nb) bsum[t] = s[t] - v;  // exclusive
}

// scan3 fused with dinv + self-loop CSR entry
__global__ void scan3(const int* __restrict__ tmp, const int* __restrict__ bsum,
                      const int* __restrict__ cnt, int* __restrict__ rowptr,
                      float* __restrict__ dinv, int* __restrict__ col, int n) {
    int i = blockIdx.x * 256 + threadIdx.x;
    if (i < n) {
        int inc = tmp[i] + bsum[blockIdx.x];   // inclusive scan of (cnt+1)
        rowptr[i + 1] = inc;
        int c1 = cnt[i] + 1;
        int r0 = inc - c1;                     // exclusive = rowptr[i]
        dinv[i] = rsqrtf((float)c1);
        col[r0] = i;                           // self-loop occupies slot 0 of row i
        if (i == 0) rowptr[0] = 0;
    }
}

// ---------------- edge fill, 4 edges/thread (4 independent atomic chains in flight) ----------------
// cnt[] (still = deg) reused as cursor via atomicSub; slots rowptr[d]+1..rowptr[d]+deg.
__global__ __launch_bounds__(256) void edgefill4(const int* __restrict__ src,
                                                 const int* __restrict__ dst,
                                                 const int* __restrict__ rowptr,
                                                 int* __restrict__ cnt,
                                                 int* __restrict__ col, int E) {
    int base = blockIdx.x * 1024 + threadIdx.x * 4;
    if (base + 3 < E) {
        int d0 = dst[base], d1 = dst[base + 1], d2 = dst[base + 2], d3 = dst[base + 3];
        int s0 = src[base], s1 = src[base + 1], s2 = src[base + 2], s3 = src[base + 3];
        int p0 = rowptr[d0] + atomicSub(&cnt[d0], 1);
        int p1 = rowptr[d1] + atomicSub(&cnt[d1], 1);
        int p2 = rowptr[d2] + atomicSub(&cnt[d2], 1);
        int p3 = rowptr[d3] + atomicSub(&cnt[d3], 1);
        col[p0] = s0; col[p1] = s1; col[p2] = s2; col[p3] = s3;
    } else {
        for (int e = base; e < E; ++e) {
            int d = dst[e];
            col[rowptr[d] + atomicSub(&cnt[d], 1)] = src[e];
        }
    }
}

// ---------------- layer-1 GEMM: H1 = half(x0 @ W1), UNSCALED ----------------
// (dinv applied per-edge in agg layer 1; lets this run independent of the CSR build)
__global__ __launch_bounds__(256) void gemm1h(const float* __restrict__ X,
                                              const float* __restrict__ W,
                                              __half* __restrict__ H, int Nrows) {
    __shared__ __align__(16) float xs[16][132];
    __shared__ __align__(16) float ws[16][128];
    int tid = threadIdx.x;
    int tx = tid & 15;
    int ty = tid >> 4;
    int row0 = blockIdx.x * 128;
    float acc[8][8] = {};
    for (int k0 = 0; k0 < 128; k0 += 16) {
        {   // stage fp32 X tile transposed
            int r = tid >> 2;
            int j = (tid & 3) * 4;
            int gr = row0 + r;
            float4 v = (gr < Nrows) ? *(const float4*)&X[(size_t)gr * 128 + k0 + j]
                                    : make_float4(0.f, 0.f, 0.f, 0.f);
            xs[j + 0][r] = v.x; xs[j + 1][r] = v.y; xs[j + 2][r] = v.z; xs[j + 3][r] = v.w;
            int gr2 = gr + 64;
            float4 u = (gr2 < Nrows) ? *(const float4*)&X[(size_t)gr2 * 128 + k0 + j]
                                     : make_float4(0.f, 0.f, 0.f, 0.f);
            xs[j + 0][r + 64] = u.x; xs[j + 1][r + 64] = u.y;
            xs[j + 2][r + 64] = u.z; xs[j + 3][r + 64] = u.w;
        }
        {
            const float4* Wv = (const float4*)&W[(size_t)k0 * 128];
            float4* wsv = (float4*)&ws[0][0];
            wsv[tid] = Wv[tid];
            wsv[tid + 256] = Wv[tid + 256];
        }
        __syncthreads();
#pragma unroll
        for (int kk = 0; kk < 16; ++kk) {
            float4 xa = *(float4*)&xs[kk][ty * 4];
            float4 xb = *(float4*)&xs[kk][ty * 4 + 64];
            float4 wa = *(float4*)&ws[kk][tx * 4];
            float4 wb = *(float4*)&ws[kk][tx * 4 + 64];
            float xr[8] = {xa.x, xa.y, xa.z, xa.w, xb.x, xb.y, xb.z, xb.w};
            float wr[8] = {wa.x, wa.y, wa.z, wa.w, wb.x, wb.y, wb.z, wb.w};
#pragma unroll
            for (int i = 0; i < 8; ++i)
#pragma unroll
                for (int j = 0; j < 8; ++j)
                    acc[i][j] += xr[i] * wr[j];
        }
        __syncthreads();
    }
    auto pk = [](float x, float y) { __half2 h = __floats2half2_rn(x, y); return *(unsigned int*)&h; };
#pragma unroll
    for (int i = 0; i < 8; ++i) {
        int gr = row0 + ((i < 4) ? (ty * 4 + i) : (64 + ty * 4 + i - 4));
        if (gr < Nrows) {
            uint2 q0 = make_uint2(pk(acc[i][0], acc[i][1]), pk(acc[i][2], acc[i][3]));
            uint2 q1 = make_uint2(pk(acc[i][4], acc[i][5]), pk(acc[i][6], acc[i][7]));
            *(uint2*)&H[(size_t)gr * 128 + tx * 4] = q0;
            *(uint2*)&H[(size_t)gr * 128 + 64 + tx * 4] = q1;
        }
    }
}

// ---------------- fp16-in GEMM: H[N,128] = half((Xh @ W) * dscale[row]) ----------------
__global__ __launch_bounds__(256) void gemm128hh(const __half* __restrict__ Xh,
                                                 const float* __restrict__ W,
                                                 const float* __restrict__ dscale,
                                                 __half* __restrict__ H, int Nrows) {
    __shared__ __align__(16) float xs[16][132];
    __shared__ __align__(16) float ws[16][128];
    int tid = threadIdx.x;
    int tx = tid & 15;
    int ty = tid >> 4;
    int row0 = blockIdx.x * 128;
    float acc[8][8] = {};
    for (int k0 = 0; k0 < 128; k0 += 16) {
        {   // stage fp16 X tile transposed: 128 rows x 16 k, 8 halfs (uint4) per thread
            int r = tid >> 1;             // 0..127
            int jj = (tid & 1) * 8;       // 0 or 8
            int gr = row0 + r;
            if (gr < Nrows) {
                uint4 rw = *(const uint4*)&Xh[(size_t)gr * 128 + k0 + jj];
                const __half2* hp = (const __half2*)&rw;
#pragma unroll
                for (int m = 0; m < 4; ++m) {
                    float2 f = __half22float2(hp[m]);
                    xs[jj + 2 * m][r] = f.x;
                    xs[jj + 2 * m + 1][r] = f.y;
                }
            } else {
#pragma unroll
                for (int m = 0; m < 8; ++m) xs[jj + m][r] = 0.f;
            }
        }
        {
            const float4* Wv = (const float4*)&W[(size_t)k0 * 128];
            float4* wsv = (float4*)&ws[0][0];
            wsv[tid] = Wv[tid];
            wsv[tid + 256] = Wv[tid + 256];
        }
        __syncthreads();
#pragma unroll
        for (int kk = 0; kk < 16; ++kk) {
            float4 xa = *(float4*)&xs[kk][ty * 4];
            float4 xb = *(float4*)&xs[kk][ty * 4 + 64];
            float4 wa = *(float4*)&ws[kk][tx * 4];
            float4 wb = *(float4*)&ws[kk][tx * 4 + 64];
            float xr[8] = {xa.x, xa.y, xa.z, xa.w, xb.x, xb.y, xb.z, xb.w};
            float wr[8] = {wa.x, wa.y, wa.z, wa.w, wb.x, wb.y, wb.z, wb.w};
#pragma unroll
            for (int i = 0; i < 8; ++i)
#pragma unroll
                for (int j = 0; j < 8; ++j)
                    acc[i][j] += xr[i] * wr[j];
        }
        __syncthreads();
    }
    auto pk = [](float x, float y) { __half2 h = __floats2half2_rn(x, y); return *(unsigned int*)&h; };
#pragma unroll
    for (int i = 0; i < 8; ++i) {
        int gr = row0 + ((i < 4) ? (ty * 4 + i) : (64 + ty * 4 + i - 4));
        if (gr < Nrows) {
            float s = dscale[gr];
            uint2 q0 = make_uint2(pk(acc[i][0] * s, acc[i][1] * s), pk(acc[i][2] * s, acc[i][3] * s));
            uint2 q1 = make_uint2(pk(acc[i][4] * s, acc[i][5] * s), pk(acc[i][6] * s, acc[i][7] * s));
            *(uint2*)&H[(size_t)gr * 128 + tx * 4] = q0;
            *(uint2*)&H[(size_t)gr * 128 + 64 + tx * 4] = q1;
        }
    }
}

// ---------------- CSR aggregation over fp16 H -> fp16 out ----------------
// gdinv=1: H unscaled, gather dinv[s] per edge (layer 1).  gdinv=0: H pre-scaled.
// out = relu?(dinv[n]*sum + b), stored fp16.  256 threads = 16 nodes x 16 lanes,
// 8 halfs (uint4) per lane.  Unroll-4 -> 4 gathers in flight.  fp32 accumulation.
__global__ __launch_bounds__(256) void agg_h(const __half* __restrict__ H,
                                             const float* __restrict__ dinv,
                                             const int* __restrict__ rowptr,
                                             const int* __restrict__ col,
                                             const float* __restrict__ bias,
                                             __half* __restrict__ out,
                                             int n, int relu, int gdinv) {
    int node = blockIdx.x * 16 + (threadIdx.x >> 4);
    int t = (threadIdx.x & 15) * 8;       // dim offset (halfs)
    if (node >= n) return;
    int beg = rowptr[node], end = rowptr[node + 1];
    float a[8] = {};
    int k = beg;
    for (; k + 4 <= end; k += 4) {
        int s0 = col[k], s1 = col[k + 1], s2 = col[k + 2], s3 = col[k + 3];
        float w0 = 1.f, w1 = 1.f, w2 = 1.f, w3 = 1.f;
        if (gdinv) { w0 = dinv[s0]; w1 = dinv[s1]; w2 = dinv[s2]; w3 = dinv[s3]; }
        uint4 r0 = *(const uint4*)&H[(size_t)s0 * 128 + t];
        uint4 r1 = *(const uint4*)&H[(size_t)s1 * 128 + t];
        uint4 r2 = *(const uint4*)&H[(size_t)s2 * 128 + t];
        uint4 r3 = *(const uint4*)&H[(size_t)s3 * 128 + t];
        const __half2* h0 = (const __half2*)&r0;
        const __half2* h1 = (const __half2*)&r1;
        const __half2* h2 = (const __half2*)&r2;
        const __half2* h3 = (const __half2*)&r3;
#pragma unroll
        for (int j = 0; j < 4; ++j) {
            float2 f0 = __half22float2(h0[j]);
            float2 f1 = __half22float2(h1[j]);
            float2 f2 = __half22float2(h2[j]);
            float2 f3 = __half22float2(h3[j]);
            a[2 * j]     += f0.x * w0 + f1.x * w1 + f2.x * w2 + f3.x * w3;
            a[2 * j + 1] += f0.y * w0 + f1.y * w1 + f2.y * w2 + f3.y * w3;
        }
    }
    for (; k < end; ++k) {
        int s0 = col[k];
        float w0 = gdinv ? dinv[s0] : 1.f;
        uint4 r0 = *(const uint4*)&H[(size_t)s0 * 128 + t];
        const __half2* h0 = (const __half2*)&r0;
#pragma unroll
        for (int j = 0; j < 4; ++j) {
            float2 f0 = __half22float2(h0[j]);
            a[2 * j] += f0.x * w0;
            a[2 * j + 1] += f0.y * w0;
        }
    }
    float dn = dinv[node];
    float4 b0 = *(const float4*)&bias[t];
    float4 b1 = *(const float4*)&bias[t + 4];
    float r0 = a[0] * dn + b0.x, r1 = a[1] * dn + b0.y;
    float r2 = a[2] * dn + b0.z, r3 = a[3] * dn + b0.w;
    float r4 = a[4] * dn + b1.x, r5 = a[5] * dn + b1.y;
    float r6 = a[6] * dn + b1.z, r7 = a[7] * dn + b1.w;
    if (relu) {
        r0 = fmaxf(r0, 0.f); r1 = fmaxf(r1, 0.f); r2 = fmaxf(r2, 0.f); r3 = fmaxf(r3, 0.f);
        r4 = fmaxf(r4, 0.f); r5 = fmaxf(r5, 0.f); r6 = fmaxf(r6, 0.f); r7 = fmaxf(r7, 0.f);
    }
    auto pk = [](float x, float y) { __half2 h = __floats2half2_rn(x, y); return *(unsigned int*)&h; };
    uint4 o = make_uint4(pk(r0, r1), pk(r2, r3), pk(r4, r5), pk(r6, r7));
    *(uint4*)&out[(size_t)node * 128 + t] = o;
}

// ---------------- edge decoder over fp16 X: out[e] = dot(X[u], X[v]) ----------------
// 16 lanes per edge, 8 halfs (uint4) per lane; fp32 accumulate; 16-lane shuffle reduce.
__global__ __launch_bounds__(256) void decoder_h(const __half* __restrict__ X,
                                                 const int* __restrict__ eli,
                                                 float* __restrict__ out, int EL) {
    int e = blockIdx.x * 16 + (threadIdx.x >> 4);
    int lane = threadIdx.x & 15;
    if (e >= EL) return;
    int u = eli[e], v = eli[EL + e];
    uint4 ra = *(const uint4*)&X[(size_t)u * 128 + lane * 8];
    uint4 rb = *(const uint4*)&X[(size_t)v * 128 + lane * 8];
    const __half2* ha = (const __half2*)&ra;
    const __half2* hb = (const __half2*)&rb;
    float d = 0.f;
#pragma unroll
    for (int j = 0; j < 4; ++j) {
        float2 fa = __half22float2(ha[j]);
        float2 fb = __half22float2(hb[j]);
        d += fa.x * fb.x + fa.y * fb.y;
    }
#pragma unroll
    for (int off = 8; off > 0; off >>= 1) d += __shfl_xor(d, off);
    if (lane == 0) out[e] = d;
}

extern "C" void kernel_launch(void* const* d_in, const int* in_sizes, int n_in,
                              void* d_out, int out_size, void* d_ws, size_t ws_size,
                              hipStream_t stream) {
    const float* x0 = (const float*)d_in[0];
    const float* W1 = (const float*)d_in[1];
    const float* b1 = (const float*)d_in[2];
    const float* W2 = (const float*)d_in[3];
    const float* b2 = (const float*)d_in[4];
    const float* W3 = (const float*)d_in[5];
    const float* b3 = (const float*)d_in[6];
    const int* ei   = (const int*)d_in[7];
    const int* eli  = (const int*)d_in[8];
    float* out = (float*)d_out;

    const int D = 128;
    const int N  = in_sizes[0] / D;
    const int E  = in_sizes[7] / 2;
    const int EL = in_sizes[8] / 2;

    const int* src = ei;        // edge_index[0]
    const int* dst = ei + E;    // edge_index[1]

    // -------- workspace carve-up (256B aligned) --------
    char* ws = (char*)d_ws;
    size_t off = 0;
    auto alloc = [&](size_t bytes) -> void* {
        off = (off + 255) & ~(size_t)255;
        void* p = ws + off;
        off += bytes;
        return p;
    };
    int*    cnt    = (int*)alloc((size_t)N * sizeof(int));
    int*    tmp    = (int*)alloc((size_t)N * sizeof(int));
    int*    bsum   = (int*)alloc(256 * sizeof(int));
    int*    rowptr = (int*)alloc((size_t)(N + 1) * sizeof(int));
    float*  dinv   = (float*)alloc((size_t)N * sizeof(float));
    int*    col    = (int*)alloc((size_t)(E + N) * sizeof(int));
    __half* hbuf   = (__half*)alloc((size_t)N * D * sizeof(__half));  // gemm out
    __half* xbuf   = (__half*)alloc((size_t)N * D * sizeof(__half));  // agg out
    (void)ws_size;

    // zero the degree counters
    hipMemsetAsync(cnt, 0, (size_t)N * sizeof(int), stream);

    int nbN = (N + 255) / 256;
    int nbE4 = (E + 1023) / 1024;
    int gemmGrid = (N + 127) / 128;
    int aggGrid  = (N + 15) / 16;

    // ---- degree histogram (full-occupancy, 4 atomic chains/thread) ----
    deg4<<<nbE4, 256, 0, stream>>>(dst, cnt, E);
    // ---- layer-1 GEMM (independent of CSR build; unscaled fp16 out) ----
    gemm1h<<<gemmGrid, 256, 0, stream>>>(x0, W1, hbuf, N);

    // ---- scan chain -> rowptr/dinv/self-loops ----
    scan1<<<nbN, 256, 0, stream>>>(cnt, tmp, bsum, N);
    scan2<<<1, 256, 0, stream>>>(bsum, nbN);
    scan3<<<nbN, 256, 0, stream>>>(tmp, bsum, cnt, rowptr, dinv, col, N);
    edgefill4<<<nbE4, 256, 0, stream>>>(src, dst, rowptr, cnt, col, E);

    // ---- layer 1: agg gathers dinv[s] per edge (H1 unscaled) ----
    agg_h<<<aggGrid, 256, 0, stream>>>(hbuf, dinv, rowptr, col, b1, xbuf, N, 1, 1);
    // ---- layer 2 ----
    gemm128hh<<<gemmGrid, 256, 0, stream>>>(xbuf, W2, dinv, hbuf, N);
    agg_h<<<aggGrid, 256, 0, stream>>>(hbuf, dinv, rowptr, col, b2, xbuf, N, 1, 0);
    // ---- layer 3 ----
    gemm128hh<<<gemmGrid, 256, 0, stream>>>(xbuf, W3, dinv, hbuf, N);
    agg_h<<<aggGrid, 256, 0, stream>>>(hbuf, dinv, rowptr, col, b3, xbuf, N, 0, 0);

    // ---- decoder ----
    decoder_h<<<(EL + 15) / 16, 256, 0, stream>>>(xbuf, eli, out, EL);
}

// Round 12
// 326.985 us; speedup vs baseline: 1.1221x; 1.1221x over previous
//
#include <hip/hip_runtime.h>
#include <hip/hip_bf16.h>
#include <hip/hip_fp16.h>

// ---------------- degree histogram + per-edge rank, 4 edges/thread ----------------
// rank[e] = #earlier-counted edges with same dst  (atomicAdd return).  After this,
// cnt[d] = deg(d).  The rank makes the later CSR fill atomic-free.
__global__ __launch_bounds__(256) void deg_rank(const int* __restrict__ dst,
                                                int* __restrict__ cnt,
                                                int* __restrict__ rank, int E) {
    int base = blockIdx.x * 1024 + threadIdx.x * 4;
    if (base + 3 < E) {
        int d0 = dst[base], d1 = dst[base + 1], d2 = dst[base + 2], d3 = dst[base + 3];
        int r0 = atomicAdd(&cnt[d0], 1);
        int r1 = atomicAdd(&cnt[d1], 1);
        int r2 = atomicAdd(&cnt[d2], 1);
        int r3 = atomicAdd(&cnt[d3], 1);
        rank[base] = r0; rank[base + 1] = r1; rank[base + 2] = r2; rank[base + 3] = r3;
    } else {
        for (int e = base; e < E; ++e) rank[e] = atomicAdd(&cnt[dst[e]], 1);
    }
}

// ---------------- scanA: per-block inclusive scan of (cnt[i]+1) ----------------
__global__ void scanA(const int* __restrict__ cnt, int* __restrict__ tmp,
                      int* __restrict__ bsum, int n) {
    __shared__ int s[256];
    int i = blockIdx.x * 256 + threadIdx.x;
    int v = (i < n) ? (cnt[i] + 1) : 0;
    s[threadIdx.x] = v;
    __syncthreads();
    for (int off = 1; off < 256; off <<= 1) {
        int x = (threadIdx.x >= off) ? s[threadIdx.x - off] : 0;
        __syncthreads();
        s[threadIdx.x] += x;
        __syncthreads();
    }
    if (i < n) tmp[i] = s[threadIdx.x];
    if (threadIdx.x == 255) bsum[blockIdx.x] = s[255];
}

// ---------------- scanB: redundant partial-scan + apply + dinv + self-loop ----------------
// Every block scans all nb (<=256) partials in LDS, takes its own exclusive prefix,
// then finalizes rowptr / dinv / self-loop for its 256 rows.  Merges old scan2+scan3.
__global__ void scanB(const int* __restrict__ tmp, const int* __restrict__ bsum,
                      const int* __restrict__ cnt, int* __restrict__ rowptr,
                      float* __restrict__ dinv, int* __restrict__ col, int n, int nb) {
    __shared__ int p[256];
    int t = threadIdx.x;
    p[t] = (t < nb) ? bsum[t] : 0;
    __syncthreads();
    for (int off = 1; off < 256; off <<= 1) {
        int x = (t >= off) ? p[t - off] : 0;
        __syncthreads();
        p[t] += x;
        __syncthreads();
    }
    int prefix = (blockIdx.x == 0) ? 0 : p[blockIdx.x - 1];
    int i = blockIdx.x * 256 + t;
    if (i < n) {
        int inc = tmp[i] + prefix;             // inclusive scan of (cnt+1)
        rowptr[i + 1] = inc;
        int c1 = cnt[i] + 1;
        dinv[i] = rsqrtf((float)c1);
        col[inc - c1] = i;                     // self-loop occupies slot 0 of row i
        if (i == 0) rowptr[0] = 0;
    }
}

// ---------------- atomic-free CSR fill: col[rowptr[d]+1+rank[e]] = src[e] ----------------
__global__ __launch_bounds__(256) void fill4(const int* __restrict__ src,
                                             const int* __restrict__ dst,
                                             const int* __restrict__ rank,
                                             const int* __restrict__ rowptr,
                                             int* __restrict__ col, int E) {
    int base = blockIdx.x * 1024 + threadIdx.x * 4;
    if (base + 3 < E) {
        int d0 = dst[base], d1 = dst[base + 1], d2 = dst[base + 2], d3 = dst[base + 3];
        int s0 = src[base], s1 = src[base + 1], s2 = src[base + 2], s3 = src[base + 3];
        int r0 = rank[base], r1 = rank[base + 1], r2 = rank[base + 2], r3 = rank[base + 3];
        col[rowptr[d0] + 1 + r0] = s0;
        col[rowptr[d1] + 1 + r1] = s1;
        col[rowptr[d2] + 1 + r2] = s2;
        col[rowptr[d3] + 1 + r3] = s3;
    } else {
        for (int e = base; e < E; ++e)
            col[rowptr[dst[e]] + 1 + rank[e]] = src[e];
    }
}

// ---------------- layer-1 GEMM: H1 = half(x0 @ W1), UNSCALED ----------------
// (dinv applied per-edge in agg layer 1; lets this run independent of the CSR build)
__global__ __launch_bounds__(256) void gemm1h(const float* __restrict__ X,
                                              const float* __restrict__ W,
                                              __half* __restrict__ H, int Nrows) {
    __shared__ __align__(16) float xs[16][132];
    __shared__ __align__(16) float ws[16][128];
    int tid = threadIdx.x;
    int tx = tid & 15;
    int ty = tid >> 4;
    int row0 = blockIdx.x * 128;
    float acc[8][8] = {};
    for (int k0 = 0; k0 < 128; k0 += 16) {
        {   // stage fp32 X tile transposed
            int r = tid >> 2;
            int j = (tid & 3) * 4;
            int gr = row0 + r;
            float4 v = (gr < Nrows) ? *(const float4*)&X[(size_t)gr * 128 + k0 + j]
                                    : make_float4(0.f, 0.f, 0.f, 0.f);
            xs[j + 0][r] = v.x; xs[j + 1][r] = v.y; xs[j + 2][r] = v.z; xs[j + 3][r] = v.w;
            int gr2 = gr + 64;
            float4 u = (gr2 < Nrows) ? *(const float4*)&X[(size_t)gr2 * 128 + k0 + j]
                                     : make_float4(0.f, 0.f, 0.f, 0.f);
            xs[j + 0][r + 64] = u.x; xs[j + 1][r + 64] = u.y;
            xs[j + 2][r + 64] = u.z; xs[j + 3][r + 64] = u.w;
        }
        {
            const float4* Wv = (const float4*)&W[(size_t)k0 * 128];
            float4* wsv = (float4*)&ws[0][0];
            wsv[tid] = Wv[tid];
            wsv[tid + 256] = Wv[tid + 256];
        }
        __syncthreads();
#pragma unroll
        for (int kk = 0; kk < 16; ++kk) {
            float4 xa = *(float4*)&xs[kk][ty * 4];
            float4 xb = *(float4*)&xs[kk][ty * 4 + 64];
            float4 wa = *(float4*)&ws[kk][tx * 4];
            float4 wb = *(float4*)&ws[kk][tx * 4 + 64];
            float xr[8] = {xa.x, xa.y, xa.z, xa.w, xb.x, xb.y, xb.z, xb.w};
            float wr[8] = {wa.x, wa.y, wa.z, wa.w, wb.x, wb.y, wb.z, wb.w};
#pragma unroll
            for (int i = 0; i < 8; ++i)
#pragma unroll
                for (int j = 0; j < 8; ++j)
                    acc[i][j] += xr[i] * wr[j];
        }
        __syncthreads();
    }
    auto pk = [](float x, float y) { __half2 h = __floats2half2_rn(x, y); return *(unsigned int*)&h; };
#pragma unroll
    for (int i = 0; i < 8; ++i) {
        int gr = row0 + ((i < 4) ? (ty * 4 + i) : (64 + ty * 4 + i - 4));
        if (gr < Nrows) {
            uint2 q0 = make_uint2(pk(acc[i][0], acc[i][1]), pk(acc[i][2], acc[i][3]));
            uint2 q1 = make_uint2(pk(acc[i][4], acc[i][5]), pk(acc[i][6], acc[i][7]));
            *(uint2*)&H[(size_t)gr * 128 + tx * 4] = q0;
            *(uint2*)&H[(size_t)gr * 128 + 64 + tx * 4] = q1;
        }
    }
}

// ---------------- fp16-in GEMM: H[N,128] = half((Xh @ W) * dscale[row]) ----------------
__global__ __launch_bounds__(256) void gemm128hh(const __half* __restrict__ Xh,
                                                 const float* __restrict__ W,
                                                 const float* __restrict__ dscale,
                                                 __half* __restrict__ H, int Nrows) {
    __shared__ __align__(16) float xs[16][132];
    __shared__ __align__(16) float ws[16][128];
    int tid = threadIdx.x;
    int tx = tid & 15;
    int ty = tid >> 4;
    int row0 = blockIdx.x * 128;
    float acc[8][8] = {};
    for (int k0 = 0; k0 < 128; k0 += 16) {
        {   // stage fp16 X tile transposed: 128 rows x 16 k, 8 halfs (uint4) per thread
            int r = tid >> 1;             // 0..127
            int jj = (tid & 1) * 8;       // 0 or 8
            int gr = row0 + r;
            if (gr < Nrows) {
                uint4 rw = *(const uint4*)&Xh[(size_t)gr * 128 + k0 + jj];
                const __half2* hp = (const __half2*)&rw;
#pragma unroll
                for (int m = 0; m < 4; ++m) {
                    float2 f = __half22float2(hp[m]);
                    xs[jj + 2 * m][r] = f.x;
                    xs[jj + 2 * m + 1][r] = f.y;
                }
            } else {
#pragma unroll
                for (int m = 0; m < 8; ++m) xs[jj + m][r] = 0.f;
            }
        }
        {
            const float4* Wv = (const float4*)&W[(size_t)k0 * 128];
            float4* wsv = (float4*)&ws[0][0];
            wsv[tid] = Wv[tid];
            wsv[tid + 256] = Wv[tid + 256];
        }
        __syncthreads();
#pragma unroll
        for (int kk = 0; kk < 16; ++kk) {
            float4 xa = *(float4*)&xs[kk][ty * 4];
            float4 xb = *(float4*)&xs[kk][ty * 4 + 64];
            float4 wa = *(float4*)&ws[kk][tx * 4];
            float4 wb = *(float4*)&ws[kk][tx * 4 + 64];
            float xr[8] = {xa.x, xa.y, xa.z, xa.w, xb.x, xb.y, xb.z, xb.w};
            float wr[8] = {wa.x, wa.y, wa.z, wa.w, wb.x, wb.y, wb.z, wb.w};
#pragma unroll
            for (int i = 0; i < 8; ++i)
#pragma unroll
                for (int j = 0; j < 8; ++j)
                    acc[i][j] += xr[i] * wr[j];
        }
        __syncthreads();
    }
    auto pk = [](float x, float y) { __half2 h = __floats2half2_rn(x, y); return *(unsigned int*)&h; };
#pragma unroll
    for (int i = 0; i < 8; ++i) {
        int gr = row0 + ((i < 4) ? (ty * 4 + i) : (64 + ty * 4 + i - 4));
        if (gr < Nrows) {
            float s = dscale[gr];
            uint2 q0 = make_uint2(pk(acc[i][0] * s, acc[i][1] * s), pk(acc[i][2] * s, acc[i][3] * s));
            uint2 q1 = make_uint2(pk(acc[i][4] * s, acc[i][5] * s), pk(acc[i][6] * s, acc[i][7] * s));
            *(uint2*)&H[(size_t)gr * 128 + tx * 4] = q0;
            *(uint2*)&H[(size_t)gr * 128 + 64 + tx * 4] = q1;
        }
    }
}

// ---------------- CSR aggregation over fp16 H -> fp16 out ----------------
// gdinv=1: H unscaled, gather dinv[s] per edge (layer 1).  gdinv=0: H pre-scaled.
// out = relu?(dinv[n]*sum + b), stored fp16.  256 threads = 16 nodes x 16 lanes,
// 8 halfs (uint4) per lane.  Unroll-4 -> 4 gathers in flight.  fp32 accumulation.
__global__ __launch_bounds__(256) void agg_h(const __half* __restrict__ H,
                                             const float* __restrict__ dinv,
                                             const int* __restrict__ rowptr,
                                             const int* __restrict__ col,
                                             const float* __restrict__ bias,
                                             __half* __restrict__ out,
                                             int n, int relu, int gdinv) {
    int node = blockIdx.x * 16 + (threadIdx.x >> 4);
    int t = (threadIdx.x & 15) * 8;       // dim offset (halfs)
    if (node >= n) return;
    int beg = rowptr[node], end = rowptr[node + 1];
    float a[8] = {};
    int k = beg;
    for (; k + 4 <= end; k += 4) {
        int s0 = col[k], s1 = col[k + 1], s2 = col[k + 2], s3 = col[k + 3];
        float w0 = 1.f, w1 = 1.f, w2 = 1.f, w3 = 1.f;
        if (gdinv) { w0 = dinv[s0]; w1 = dinv[s1]; w2 = dinv[s2]; w3 = dinv[s3]; }
        uint4 r0 = *(const uint4*)&H[(size_t)s0 * 128 + t];
        uint4 r1 = *(const uint4*)&H[(size_t)s1 * 128 + t];
        uint4 r2 = *(const uint4*)&H[(size_t)s2 * 128 + t];
        uint4 r3 = *(const uint4*)&H[(size_t)s3 * 128 + t];
        const __half2* h0 = (const __half2*)&r0;
        const __half2* h1 = (const __half2*)&r1;
        const __half2* h2 = (const __half2*)&r2;
        const __half2* h3 = (const __half2*)&r3;
#pragma unroll
        for (int j = 0; j < 4; ++j) {
            float2 f0 = __half22float2(h0[j]);
            float2 f1 = __half22float2(h1[j]);
            float2 f2 = __half22float2(h2[j]);
            float2 f3 = __half22float2(h3[j]);
            a[2 * j]     += f0.x * w0 + f1.x * w1 + f2.x * w2 + f3.x * w3;
            a[2 * j + 1] += f0.y * w0 + f1.y * w1 + f2.y * w2 + f3.y * w3;
        }
    }
    for (; k < end; ++k) {
        int s0 = col[k];
        float w0 = gdinv ? dinv[s0] : 1.f;
        uint4 r0 = *(const uint4*)&H[(size_t)s0 * 128 + t];
        const __half2* h0 = (const __half2*)&r0;
#pragma unroll
        for (int j = 0; j < 4; ++j) {
            float2 f0 = __half22float2(h0[j]);
            a[2 * j] += f0.x * w0;
            a[2 * j + 1] += f0.y * w0;
        }
    }
    float dn = dinv[node];
    float4 b0 = *(const float4*)&bias[t];
    float4 b1 = *(const float4*)&bias[t + 4];
    float r0 = a[0] * dn + b0.x, r1 = a[1] * dn + b0.y;
    float r2 = a[2] * dn + b0.z, r3 = a[3] * dn + b0.w;
    float r4 = a[4] * dn + b1.x, r5 = a[5] * dn + b1.y;
    float r6 = a[6] * dn + b1.z, r7 = a[7] * dn + b1.w;
    if (relu) {
        r0 = fmaxf(r0, 0.f); r1 = fmaxf(r1, 0.f); r2 = fmaxf(r2, 0.f); r3 = fmaxf(r3, 0.f);
        r4 = fmaxf(r4, 0.f); r5 = fmaxf(r5, 0.f); r6 = fmaxf(r6, 0.f); r7 = fmaxf(r7, 0.f);
    }
    auto pk = [](float x, float y) { __half2 h = __floats2half2_rn(x, y); return *(unsigned int*)&h; };
    uint4 o = make_uint4(pk(r0, r1), pk(r2, r3), pk(r4, r5), pk(r6, r7));
    *(uint4*)&out[(size_t)node * 128 + t] = o;
}

// ---------------- edge decoder over fp16 X: out[e] = dot(X[u], X[v]) ----------------
// 16 lanes per edge, 8 halfs (uint4) per lane; fp32 accumulate; 16-lane shuffle reduce.
__global__ __launch_bounds__(256) void decoder_h(const __half* __restrict__ X,
                                                 const int* __restrict__ eli,
                                                 float* __restrict__ out, int EL) {
    int e = blockIdx.x * 16 + (threadIdx.x >> 4);
    int lane = threadIdx.x & 15;
    if (e >= EL) return;
    int u = eli[e], v = eli[EL + e];
    uint4 ra = *(const uint4*)&X[(size_t)u * 128 + lane * 8];
    uint4 rb = *(const uint4*)&X[(size_t)v * 128 + lane * 8];
    const __half2* ha = (const __half2*)&ra;
    const __half2* hb = (const __half2*)&rb;
    float d = 0.f;
#pragma unroll
    for (int j = 0; j < 4; ++j) {
        float2 fa = __half22float2(ha[j]);
        float2 fb = __half22float2(hb[j]);
        d += fa.x * fb.x + fa.y * fb.y;
    }
#pragma unroll
    for (int off = 8; off > 0; off >>= 1) d += __shfl_xor(d, off);
    if (lane == 0) out[e] = d;
}

extern "C" void kernel_launch(void* const* d_in, const int* in_sizes, int n_in,
                              void* d_out, int out_size, void* d_ws, size_t ws_size,
                              hipStream_t stream) {
    const float* x0 = (const float*)d_in[0];
    const float* W1 = (const float*)d_in[1];
    const float* b1 = (const float*)d_in[2];
    const float* W2 = (const float*)d_in[3];
    const float* b2 = (const float*)d_in[4];
    const float* W3 = (const float*)d_in[5];
    const float* b3 = (const float*)d_in[6];
    const int* ei   = (const int*)d_in[7];
    const int* eli  = (const int*)d_in[8];
    float* out = (float*)d_out;

    const int D = 128;
    const int N  = in_sizes[0] / D;
    const int E  = in_sizes[7] / 2;
    const int EL = in_sizes[8] / 2;

    const int* src = ei;        // edge_index[0]
    const int* dst = ei + E;    // edge_index[1]

    // -------- workspace carve-up (256B aligned) --------
    char* ws = (char*)d_ws;
    size_t off = 0;
    auto alloc = [&](size_t bytes) -> void* {
        off = (off + 255) & ~(size_t)255;
        void* p = ws + off;
        off += bytes;
        return p;
    };
    int*    cnt    = (int*)alloc((size_t)N * sizeof(int));
    int*    tmp    = (int*)alloc((size_t)N * sizeof(int));
    int*    bsum   = (int*)alloc(256 * sizeof(int));
    int*    rowptr = (int*)alloc((size_t)(N + 1) * sizeof(int));
    float*  dinv   = (float*)alloc((size_t)N * sizeof(float));
    int*    rank   = (int*)alloc((size_t)E * sizeof(int));
    int*    col    = (int*)alloc((size_t)(E + N) * sizeof(int));
    __half* hbuf   = (__half*)alloc((size_t)N * D * sizeof(__half));  // gemm out
    __half* xbuf   = (__half*)alloc((size_t)N * D * sizeof(__half));  // agg out
    (void)ws_size;

    // zero the degree counters
    hipMemsetAsync(cnt, 0, (size_t)N * sizeof(int), stream);

    int nbN = (N + 255) / 256;
    int nbE4 = (E + 1023) / 1024;
    int gemmGrid = (N + 127) / 128;
    int aggGrid  = (N + 15) / 16;

    // ---- degree histogram + rank capture (single atomic pass over edges) ----
    deg_rank<<<nbE4, 256, 0, stream>>>(dst, cnt, rank, E);
    // ---- layer-1 GEMM (independent of CSR build; unscaled fp16 out) ----
    gemm1h<<<gemmGrid, 256, 0, stream>>>(x0, W1, hbuf, N);

    // ---- scan (2 dispatches) -> rowptr/dinv/self-loops ----
    scanA<<<nbN, 256, 0, stream>>>(cnt, tmp, bsum, N);
    scanB<<<nbN, 256, 0, stream>>>(tmp, bsum, cnt, rowptr, dinv, col, N, nbN);
    // ---- atomic-free CSR fill ----
    fill4<<<nbE4, 256, 0, stream>>>(src, dst, rank, rowptr, col, E);

    // ---- layer 1: agg gathers dinv[s] per edge (H1 unscaled) ----
    agg_h<<<aggGrid, 256, 0, stream>>>(hbuf, dinv, rowptr, col, b1, xbuf, N, 1, 1);
    // ---- layer 2 ----
    gemm128hh<<<gemmGrid, 256, 0, stream>>>(xbuf, W2, dinv, hbuf, N);
    agg_h<<<aggGrid, 256, 0, stream>>>(hbuf, dinv, rowptr, col, b2, xbuf, N, 1, 0);
    // ---- layer 3 ----
    gemm128hh<<<gemmGrid, 256, 0, stream>>>(xbuf, W3, dinv, hbuf, N);
    agg_h<<<aggGrid, 256, 0, stream>>>(hbuf, dinv, rowptr, col, b3, xbuf, N, 0, 0);

    // ---- decoder ----
    decoder_h<<<(EL + 15) / 16, 256, 0, stream>>>(xbuf, eli, out, EL);
}

// Round 13
// 319.320 us; speedup vs baseline: 1.1491x; 1.0240x over previous
//
#include <hip/hip_runtime.h>
#include <hip/hip_bf16.h>
#include <hip/hip_fp16.h>

// ---------------- FUSED: layer-1 GEMM (blocks first) + degree/rank atomic pass ----------------
// Blocks [0, gemmBlocks): H1 = half(x0 @ W1), UNSCALED (dinv applied per-edge in agg L1).
// Blocks [gemmBlocks, ...): rank[e] = atomicAdd(&cnt[dst[e]],1), 4 edges/thread.
// GEMM blocks dispatch first so CUs fill with VALU-heavy waves; the atomic waves'
// ~1000-cyc latencies co-schedule under them (m114 pipe overlap) instead of
// occupying CUs idle (round-10 failure had deg first -> serialized sum).
__global__ __launch_bounds__(256) void gemm1_deg(const float* __restrict__ X,
                                                 const float* __restrict__ W,
                                                 __half* __restrict__ H, int Nrows,
                                                 int gemmBlocks,
                                                 const int* __restrict__ dst,
                                                 int* __restrict__ cnt,
                                                 int* __restrict__ rank, int E) {
    int tid = threadIdx.x;
    if (blockIdx.x >= gemmBlocks) {
        int base = (blockIdx.x - gemmBlocks) * 1024 + tid * 4;
        if (base + 3 < E) {
            int d0 = dst[base], d1 = dst[base + 1], d2 = dst[base + 2], d3 = dst[base + 3];
            int r0 = atomicAdd(&cnt[d0], 1);
            int r1 = atomicAdd(&cnt[d1], 1);
            int r2 = atomicAdd(&cnt[d2], 1);
            int r3 = atomicAdd(&cnt[d3], 1);
            rank[base] = r0; rank[base + 1] = r1; rank[base + 2] = r2; rank[base + 3] = r3;
        } else {
            for (int e = base; e < E; ++e) rank[e] = atomicAdd(&cnt[dst[e]], 1);
        }
        return;
    }
    __shared__ __align__(16) float xs[16][132];
    __shared__ __align__(16) float ws[16][128];
    int tx = tid & 15;
    int ty = tid >> 4;
    int row0 = blockIdx.x * 128;
    float acc[8][8] = {};
    for (int k0 = 0; k0 < 128; k0 += 16) {
        {   // stage fp32 X tile transposed
            int r = tid >> 2;
            int j = (tid & 3) * 4;
            int gr = row0 + r;
            float4 v = (gr < Nrows) ? *(const float4*)&X[(size_t)gr * 128 + k0 + j]
                                    : make_float4(0.f, 0.f, 0.f, 0.f);
            xs[j + 0][r] = v.x; xs[j + 1][r] = v.y; xs[j + 2][r] = v.z; xs[j + 3][r] = v.w;
            int gr2 = gr + 64;
            float4 u = (gr2 < Nrows) ? *(const float4*)&X[(size_t)gr2 * 128 + k0 + j]
                                     : make_float4(0.f, 0.f, 0.f, 0.f);
            xs[j + 0][r + 64] = u.x; xs[j + 1][r + 64] = u.y;
            xs[j + 2][r + 64] = u.z; xs[j + 3][r + 64] = u.w;
        }
        {
            const float4* Wv = (const float4*)&W[(size_t)k0 * 128];
            float4* wsv = (float4*)&ws[0][0];
            wsv[tid] = Wv[tid];
            wsv[tid + 256] = Wv[tid + 256];
        }
        __syncthreads();
#pragma unroll
        for (int kk = 0; kk < 16; ++kk) {
            float4 xa = *(float4*)&xs[kk][ty * 4];
            float4 xb = *(float4*)&xs[kk][ty * 4 + 64];
            float4 wa = *(float4*)&ws[kk][tx * 4];
            float4 wb = *(float4*)&ws[kk][tx * 4 + 64];
            float xr[8] = {xa.x, xa.y, xa.z, xa.w, xb.x, xb.y, xb.z, xb.w};
            float wr[8] = {wa.x, wa.y, wa.z, wa.w, wb.x, wb.y, wb.z, wb.w};
#pragma unroll
            for (int i = 0; i < 8; ++i)
#pragma unroll
                for (int j = 0; j < 8; ++j)
                    acc[i][j] += xr[i] * wr[j];
        }
        __syncthreads();
    }
    auto pk = [](float x, float y) { __half2 h = __floats2half2_rn(x, y); return *(unsigned int*)&h; };
#pragma unroll
    for (int i = 0; i < 8; ++i) {
        int gr = row0 + ((i < 4) ? (ty * 4 + i) : (64 + ty * 4 + i - 4));
        if (gr < Nrows) {
            uint2 q0 = make_uint2(pk(acc[i][0], acc[i][1]), pk(acc[i][2], acc[i][3]));
            uint2 q1 = make_uint2(pk(acc[i][4], acc[i][5]), pk(acc[i][6], acc[i][7]));
            *(uint2*)&H[(size_t)gr * 128 + tx * 4] = q0;
            *(uint2*)&H[(size_t)gr * 128 + 64 + tx * 4] = q1;
        }
    }
}

// ---------------- scanA: per-block inclusive scan of (cnt[i]+1) ----------------
__global__ void scanA(const int* __restrict__ cnt, int* __restrict__ tmp,
                      int* __restrict__ bsum, int n) {
    __shared__ int s[256];
    int i = blockIdx.x * 256 + threadIdx.x;
    int v = (i < n) ? (cnt[i] + 1) : 0;
    s[threadIdx.x] = v;
    __syncthreads();
    for (int off = 1; off < 256; off <<= 1) {
        int x = (threadIdx.x >= off) ? s[threadIdx.x - off] : 0;
        __syncthreads();
        s[threadIdx.x] += x;
        __syncthreads();
    }
    if (i < n) tmp[i] = s[threadIdx.x];
    if (threadIdx.x == 255) bsum[blockIdx.x] = s[255];
}

// ---------------- scanB: redundant partial-scan + apply + dinv + self-loop ----------------
__global__ void scanB(const int* __restrict__ tmp, const int* __restrict__ bsum,
                      const int* __restrict__ cnt, int* __restrict__ rowptr,
                      float* __restrict__ dinv, int* __restrict__ col, int n, int nb) {
    __shared__ int p[256];
    int t = threadIdx.x;
    p[t] = (t < nb) ? bsum[t] : 0;
    __syncthreads();
    for (int off = 1; off < 256; off <<= 1) {
        int x = (t >= off) ? p[t - off] : 0;
        __syncthreads();
        p[t] += x;
        __syncthreads();
    }
    int prefix = (blockIdx.x == 0) ? 0 : p[blockIdx.x - 1];
    int i = blockIdx.x * 256 + t;
    if (i < n) {
        int inc = tmp[i] + prefix;             // inclusive scan of (cnt+1)
        rowptr[i + 1] = inc;
        int c1 = cnt[i] + 1;
        dinv[i] = rsqrtf((float)c1);
        col[inc - c1] = i;                     // self-loop occupies slot 0 of row i
        if (i == 0) rowptr[0] = 0;
    }
}

// ---------------- atomic-free CSR fill: col[rowptr[d]+1+rank[e]] = src[e] ----------------
__global__ __launch_bounds__(256) void fill4(const int* __restrict__ src,
                                             const int* __restrict__ dst,
                                             const int* __restrict__ rank,
                                             const int* __restrict__ rowptr,
                                             int* __restrict__ col, int E) {
    int base = blockIdx.x * 1024 + threadIdx.x * 4;
    if (base + 3 < E) {
        int d0 = dst[base], d1 = dst[base + 1], d2 = dst[base + 2], d3 = dst[base + 3];
        int s0 = src[base], s1 = src[base + 1], s2 = src[base + 2], s3 = src[base + 3];
        int r0 = rank[base], r1 = rank[base + 1], r2 = rank[base + 2], r3 = rank[base + 3];
        col[rowptr[d0] + 1 + r0] = s0;
        col[rowptr[d1] + 1 + r1] = s1;
        col[rowptr[d2] + 1 + r2] = s2;
        col[rowptr[d3] + 1 + r3] = s3;
    } else {
        for (int e = base; e < E; ++e)
            col[rowptr[dst[e]] + 1 + rank[e]] = src[e];
    }
}

// ---------------- fp16-in GEMM: H[N,128] = half((Xh @ W) * dscale[row]) ----------------
__global__ __launch_bounds__(256) void gemm128hh(const __half* __restrict__ Xh,
                                                 const float* __restrict__ W,
                                                 const float* __restrict__ dscale,
                                                 __half* __restrict__ H, int Nrows) {
    __shared__ __align__(16) float xs[16][132];
    __shared__ __align__(16) float ws[16][128];
    int tid = threadIdx.x;
    int tx = tid & 15;
    int ty = tid >> 4;
    int row0 = blockIdx.x * 128;
    float acc[8][8] = {};
    for (int k0 = 0; k0 < 128; k0 += 16) {
        {   // stage fp16 X tile transposed: 128 rows x 16 k, 8 halfs (uint4) per thread
            int r = tid >> 1;             // 0..127
            int jj = (tid & 1) * 8;       // 0 or 8
            int gr = row0 + r;
            if (gr < Nrows) {
                uint4 rw = *(const uint4*)&Xh[(size_t)gr * 128 + k0 + jj];
                const __half2* hp = (const __half2*)&rw;
#pragma unroll
                for (int m = 0; m < 4; ++m) {
                    float2 f = __half22float2(hp[m]);
                    xs[jj + 2 * m][r] = f.x;
                    xs[jj + 2 * m + 1][r] = f.y;
                }
            } else {
#pragma unroll
                for (int m = 0; m < 8; ++m) xs[jj + m][r] = 0.f;
            }
        }
        {
            const float4* Wv = (const float4*)&W[(size_t)k0 * 128];
            float4* wsv = (float4*)&ws[0][0];
            wsv[tid] = Wv[tid];
            wsv[tid + 256] = Wv[tid + 256];
        }
        __syncthreads();
#pragma unroll
        for (int kk = 0; kk < 16; ++kk) {
            float4 xa = *(float4*)&xs[kk][ty * 4];
            float4 xb = *(float4*)&xs[kk][ty * 4 + 64];
            float4 wa = *(float4*)&ws[kk][tx * 4];
            float4 wb = *(float4*)&ws[kk][tx * 4 + 64];
            float xr[8] = {xa.x, xa.y, xa.z, xa.w, xb.x, xb.y, xb.z, xb.w};
            float wr[8] = {wa.x, wa.y, wa.z, wa.w, wb.x, wb.y, wb.z, wb.w};
#pragma unroll
            for (int i = 0; i < 8; ++i)
#pragma unroll
                for (int j = 0; j < 8; ++j)
                    acc[i][j] += xr[i] * wr[j];
        }
        __syncthreads();
    }
    auto pk = [](float x, float y) { __half2 h = __floats2half2_rn(x, y); return *(unsigned int*)&h; };
#pragma unroll
    for (int i = 0; i < 8; ++i) {
        int gr = row0 + ((i < 4) ? (ty * 4 + i) : (64 + ty * 4 + i - 4));
        if (gr < Nrows) {
            float s = dscale[gr];
            uint2 q0 = make_uint2(pk(acc[i][0] * s, acc[i][1] * s), pk(acc[i][2] * s, acc[i][3] * s));
            uint2 q1 = make_uint2(pk(acc[i][4] * s, acc[i][5] * s), pk(acc[i][6] * s, acc[i][7] * s));
            *(uint2*)&H[(size_t)gr * 128 + tx * 4] = q0;
            *(uint2*)&H[(size_t)gr * 128 + 64 + tx * 4] = q1;
        }
    }
}

// ---------------- CSR aggregation over fp16 H -> fp16 out, unroll-8 ----------------
// gdinv=1: H unscaled, gather dinv[s] per edge (layer 1).  gdinv=0: H pre-scaled.
// 256 threads = 16 nodes x 16 lanes, 8 halfs (uint4) per lane.  8/4/1 tail
// structure -> up to 8 independent dwordx4 gathers in flight.  fp32 accumulation.
__global__ __launch_bounds__(256) void agg_h(const __half* __restrict__ H,
                                             const float* __restrict__ dinv,
                                             const int* __restrict__ rowptr,
                                             const int* __restrict__ col,
                                             const float* __restrict__ bias,
                                             __half* __restrict__ out,
                                             int n, int relu, int gdinv) {
    int node = blockIdx.x * 16 + (threadIdx.x >> 4);
    int t = (threadIdx.x & 15) * 8;       // dim offset (halfs)
    if (node >= n) return;
    int beg = rowptr[node], end = rowptr[node + 1];
    float a[8] = {};
    int k = beg;
    for (; k + 8 <= end; k += 8) {
        int s[8];
#pragma unroll
        for (int j = 0; j < 8; ++j) s[j] = col[k + j];
        uint4 r[8];
#pragma unroll
        for (int j = 0; j < 8; ++j) r[j] = *(const uint4*)&H[(size_t)s[j] * 128 + t];
        float w[8];
#pragma unroll
        for (int j = 0; j < 8; ++j) w[j] = gdinv ? dinv[s[j]] : 1.f;
#pragma unroll
        for (int j = 0; j < 8; ++j) {
            const __half2* h = (const __half2*)&r[j];
#pragma unroll
            for (int m = 0; m < 4; ++m) {
                float2 f = __half22float2(h[m]);
                a[2 * m] += f.x * w[j];
                a[2 * m + 1] += f.y * w[j];
            }
        }
    }
    for (; k + 4 <= end; k += 4) {
        int s0 = col[k], s1 = col[k + 1], s2 = col[k + 2], s3 = col[k + 3];
        float w0 = 1.f, w1 = 1.f, w2 = 1.f, w3 = 1.f;
        if (gdinv) { w0 = dinv[s0]; w1 = dinv[s1]; w2 = dinv[s2]; w3 = dinv[s3]; }
        uint4 r0 = *(const uint4*)&H[(size_t)s0 * 128 + t];
        uint4 r1 = *(const uint4*)&H[(size_t)s1 * 128 + t];
        uint4 r2 = *(const uint4*)&H[(size_t)s2 * 128 + t];
        uint4 r3 = *(const uint4*)&H[(size_t)s3 * 128 + t];
        const __half2* h0 = (const __half2*)&r0;
        const __half2* h1 = (const __half2*)&r1;
        const __half2* h2 = (const __half2*)&r2;
        const __half2* h3 = (const __half2*)&r3;
#pragma unroll
        for (int m = 0; m < 4; ++m) {
            float2 f0 = __half22float2(h0[m]);
            float2 f1 = __half22float2(h1[m]);
            float2 f2 = __half22float2(h2[m]);
            float2 f3 = __half22float2(h3[m]);
            a[2 * m]     += f0.x * w0 + f1.x * w1 + f2.x * w2 + f3.x * w3;
            a[2 * m + 1] += f0.y * w0 + f1.y * w1 + f2.y * w2 + f3.y * w3;
        }
    }
    for (; k < end; ++k) {
        int s0 = col[k];
        float w0 = gdinv ? dinv[s0] : 1.f;
        uint4 r0 = *(const uint4*)&H[(size_t)s0 * 128 + t];
        const __half2* h0 = (const __half2*)&r0;
#pragma unroll
        for (int m = 0; m < 4; ++m) {
            float2 f0 = __half22float2(h0[m]);
            a[2 * m] += f0.x * w0;
            a[2 * m + 1] += f0.y * w0;
        }
    }
    float dn = dinv[node];
    float4 b0 = *(const float4*)&bias[t];
    float4 b1 = *(const float4*)&bias[t + 4];
    float r0 = a[0] * dn + b0.x, r1 = a[1] * dn + b0.y;
    float r2 = a[2] * dn + b0.z, r3 = a[3] * dn + b0.w;
    float r4 = a[4] * dn + b1.x, r5 = a[5] * dn + b1.y;
    float r6 = a[6] * dn + b1.z, r7 = a[7] * dn + b1.w;
    if (relu) {
        r0 = fmaxf(r0, 0.f); r1 = fmaxf(r1, 0.f); r2 = fmaxf(r2, 0.f); r3 = fmaxf(r3, 0.f);
        r4 = fmaxf(r4, 0.f); r5 = fmaxf(r5, 0.f); r6 = fmaxf(r6, 0.f); r7 = fmaxf(r7, 0.f);
    }
    auto pk = [](float x, float y) { __half2 h = __floats2half2_rn(x, y); return *(unsigned int*)&h; };
    uint4 o = make_uint4(pk(r0, r1), pk(r2, r3), pk(r4, r5), pk(r6, r7));
    *(uint4*)&out[(size_t)node * 128 + t] = o;
}

// ---------------- edge decoder over fp16 X: out[e] = dot(X[u], X[v]) ----------------
__global__ __launch_bounds__(256) void decoder_h(const __half* __restrict__ X,
                                                 const int* __restrict__ eli,
                                                 float* __restrict__ out, int EL) {
    int e = blockIdx.x * 16 + (threadIdx.x >> 4);
    int lane = threadIdx.x & 15;
    if (e >= EL) return;
    int u = eli[e], v = eli[EL + e];
    uint4 ra = *(const uint4*)&X[(size_t)u * 128 + lane * 8];
    uint4 rb = *(const uint4*)&X[(size_t)v * 128 + lane * 8];
    const __half2* ha = (const __half2*)&ra;
    const __half2* hb = (const __half2*)&rb;
    float d = 0.f;
#pragma unroll
    for (int j = 0; j < 4; ++j) {
        float2 fa = __half22float2(ha[j]);
        float2 fb = __half22float2(hb[j]);
        d += fa.x * fb.x + fa.y * fb.y;
    }
#pragma unroll
    for (int off = 8; off > 0; off >>= 1) d += __shfl_xor(d, off);
    if (lane == 0) out[e] = d;
}

extern "C" void kernel_launch(void* const* d_in, const int* in_sizes, int n_in,
                              void* d_out, int out_size, void* d_ws, size_t ws_size,
                              hipStream_t stream) {
    const float* x0 = (const float*)d_in[0];
    const float* W1 = (const float*)d_in[1];
    const float* b1 = (const float*)d_in[2];
    const float* W2 = (const float*)d_in[3];
    const float* b2 = (const float*)d_in[4];
    const float* W3 = (const float*)d_in[5];
    const float* b3 = (const float*)d_in[6];
    const int* ei   = (const int*)d_in[7];
    const int* eli  = (const int*)d_in[8];
    float* out = (float*)d_out;

    const int D = 128;
    const int N  = in_sizes[0] / D;
    const int E  = in_sizes[7] / 2;
    const int EL = in_sizes[8] / 2;

    const int* src = ei;        // edge_index[0]
    const int* dst = ei + E;    // edge_index[1]

    // -------- workspace carve-up (256B aligned) --------
    char* ws = (char*)d_ws;
    size_t off = 0;
    auto alloc = [&](size_t bytes) -> void* {
        off = (off + 255) & ~(size_t)255;
        void* p = ws + off;
        off += bytes;
        return p;
    };
    int*    cnt    = (int*)alloc((size_t)N * sizeof(int));
    int*    tmp    = (int*)alloc((size_t)N * sizeof(int));
    int*    bsum   = (int*)alloc(256 * sizeof(int));
    int*    rowptr = (int*)alloc((size_t)(N + 1) * sizeof(int));
    float*  dinv   = (float*)alloc((size_t)N * sizeof(float));
    int*    rank   = (int*)alloc((size_t)E * sizeof(int));
    int*    col    = (int*)alloc((size_t)(E + N) * sizeof(int));
    __half* hbuf   = (__half*)alloc((size_t)N * D * sizeof(__half));  // gemm out
    __half* xbuf   = (__half*)alloc((size_t)N * D * sizeof(__half));  // agg out
    (void)ws_size;

    // zero the degree counters
    hipMemsetAsync(cnt, 0, (size_t)N * sizeof(int), stream);

    int nbN = (N + 255) / 256;
    int nbE4 = (E + 1023) / 1024;
    int gemmGrid = (N + 127) / 128;
    int aggGrid  = (N + 15) / 16;

    // ---- FUSED: layer-1 GEMM (blocks first) + degree/rank atomic pass ----
    gemm1_deg<<<gemmGrid + nbE4, 256, 0, stream>>>(x0, W1, hbuf, N, gemmGrid,
                                                   dst, cnt, rank, E);

    // ---- scan (2 dispatches) -> rowptr/dinv/self-loops ----
    scanA<<<nbN, 256, 0, stream>>>(cnt, tmp, bsum, N);
    scanB<<<nbN, 256, 0, stream>>>(tmp, bsum, cnt, rowptr, dinv, col, N, nbN);
    // ---- atomic-free CSR fill ----
    fill4<<<nbE4, 256, 0, stream>>>(src, dst, rank, rowptr, col, E);

    // ---- layer 1: agg gathers dinv[s] per edge (H1 unscaled) ----
    agg_h<<<aggGrid, 256, 0, stream>>>(hbuf, dinv, rowptr, col, b1, xbuf, N, 1, 1);
    // ---- layer 2 ----
    gemm128hh<<<gemmGrid, 256, 0, stream>>>(xbuf, W2, dinv, hbuf, N);
    agg_h<<<aggGrid, 256, 0, stream>>>(hbuf, dinv, rowptr, col, b2, xbuf, N, 1, 0);
    // ---- layer 3 ----
    gemm128hh<<<gemmGrid, 256, 0, stream>>>(xbuf, W3, dinv, hbuf, N);
    agg_h<<<aggGrid, 256, 0, stream>>>(hbuf, dinv, rowptr, col, b3, xbuf, N, 0, 0);

    // ---- decoder ----
    decoder_h<<<(EL + 15) / 16, 256, 0, stream>>>(xbuf, eli, out, EL);
}

// Round 14
// 288.011 us; speedup vs baseline: 1.2740x; 1.1087x over previous
//
#include <hip/hip_runtime.h>
#include <hip/hip_bf16.h>
#include <hip/hip_fp16.h>

typedef _Float16 v8h __attribute__((ext_vector_type(8)));
typedef float v4f __attribute__((ext_vector_type(4)));

// ---------------- FUSED: layer-1 GEMM + degree/rank atomic pass + W2/W3 frag-swizzle ----------------
// Blocks [0, gemmBlocks): H1 = half(x0 @ W1), UNSCALED (dinv applied per-edge in agg L1).
// Blocks [gemmBlocks, gemmBlocks+degBlocks): rank[e] = atomicAdd(&cnt[dst[e]],1), 4 edges/thread.
// Blocks [gemmBlocks+degBlocks, +128): repack W2,W3 (fp32) into fp16 MFMA B-fragment order:
//   wfrag[w][((c*4+s)*64 + quad*16 + n)*8 + j] = W[k= s*32+quad*8+j][c*16+n]
// so a wave's frag load at lane l is wfrag + ((c*4+s)*64 + l)*8  -> coalesced 1KB/instr.
__global__ __launch_bounds__(256) void gemm1_deg(const float* __restrict__ X,
                                                 const float* __restrict__ W,
                                                 __half* __restrict__ H, int Nrows,
                                                 int gemmBlocks, int degBlocks,
                                                 const int* __restrict__ dst,
                                                 int* __restrict__ cnt,
                                                 int* __restrict__ rank, int E,
                                                 const float* __restrict__ W2,
                                                 const float* __restrict__ W3,
                                                 __half* __restrict__ wfrag) {
    int tid = threadIdx.x;
    if (blockIdx.x >= gemmBlocks + degBlocks) {
        // ---- W2/W3 fragment swizzle: 2*16384 elements over 128 blocks ----
        int o = (blockIdx.x - gemmBlocks - degBlocks) * 256 + tid;
        int w = o >> 14, r = o & 16383;
        const float* Ws = w ? W3 : W2;
        int k = r >> 7, ncol = r & 127;
        int c = ncol >> 4, nl = ncol & 15;
        int s = k >> 5, quad = (k >> 3) & 3, j = k & 7;
        int di = ((c * 4 + s) * 64 + quad * 16 + nl) * 8 + j;
        wfrag[(size_t)w * 16384 + di] = __float2half_rn(Ws[r]);
        return;
    }
    if (blockIdx.x >= gemmBlocks) {
        int base = (blockIdx.x - gemmBlocks) * 1024 + tid * 4;
        if (base + 3 < E) {
            int d0 = dst[base], d1 = dst[base + 1], d2 = dst[base + 2], d3 = dst[base + 3];
            int r0 = atomicAdd(&cnt[d0], 1);
            int r1 = atomicAdd(&cnt[d1], 1);
            int r2 = atomicAdd(&cnt[d2], 1);
            int r3 = atomicAdd(&cnt[d3], 1);
            rank[base] = r0; rank[base + 1] = r1; rank[base + 2] = r2; rank[base + 3] = r3;
        } else {
            for (int e = base; e < E; ++e) rank[e] = atomicAdd(&cnt[dst[e]], 1);
        }
        return;
    }
    __shared__ __align__(16) float xs[16][132];
    __shared__ __align__(16) float ws[16][128];
    int tx = tid & 15;
    int ty = tid >> 4;
    int row0 = blockIdx.x * 128;
    float acc[8][8] = {};
    for (int k0 = 0; k0 < 128; k0 += 16) {
        {   // stage fp32 X tile transposed
            int r = tid >> 2;
            int j = (tid & 3) * 4;
            int gr = row0 + r;
            float4 v = (gr < Nrows) ? *(const float4*)&X[(size_t)gr * 128 + k0 + j]
                                    : make_float4(0.f, 0.f, 0.f, 0.f);
            xs[j + 0][r] = v.x; xs[j + 1][r] = v.y; xs[j + 2][r] = v.z; xs[j + 3][r] = v.w;
            int gr2 = gr + 64;
            float4 u = (gr2 < Nrows) ? *(const float4*)&X[(size_t)gr2 * 128 + k0 + j]
                                     : make_float4(0.f, 0.f, 0.f, 0.f);
            xs[j + 0][r + 64] = u.x; xs[j + 1][r + 64] = u.y;
            xs[j + 2][r + 64] = u.z; xs[j + 3][r + 64] = u.w;
        }
        {
            const float4* Wv = (const float4*)&W[(size_t)k0 * 128];
            float4* wsv = (float4*)&ws[0][0];
            wsv[tid] = Wv[tid];
            wsv[tid + 256] = Wv[tid + 256];
        }
        __syncthreads();
#pragma unroll
        for (int kk = 0; kk < 16; ++kk) {
            float4 xa = *(float4*)&xs[kk][ty * 4];
            float4 xb = *(float4*)&xs[kk][ty * 4 + 64];
            float4 wa = *(float4*)&ws[kk][tx * 4];
            float4 wb = *(float4*)&ws[kk][tx * 4 + 64];
            float xr[8] = {xa.x, xa.y, xa.z, xa.w, xb.x, xb.y, xb.z, xb.w};
            float wr[8] = {wa.x, wa.y, wa.z, wa.w, wb.x, wb.y, wb.z, wb.w};
#pragma unroll
            for (int i = 0; i < 8; ++i)
#pragma unroll
                for (int j = 0; j < 8; ++j)
                    acc[i][j] += xr[i] * wr[j];
        }
        __syncthreads();
    }
    auto pk = [](float x, float y) { __half2 h = __floats2half2_rn(x, y); return *(unsigned int*)&h; };
#pragma unroll
    for (int i = 0; i < 8; ++i) {
        int gr = row0 + ((i < 4) ? (ty * 4 + i) : (64 + ty * 4 + i - 4));
        if (gr < Nrows) {
            uint2 q0 = make_uint2(pk(acc[i][0], acc[i][1]), pk(acc[i][2], acc[i][3]));
            uint2 q1 = make_uint2(pk(acc[i][4], acc[i][5]), pk(acc[i][6], acc[i][7]));
            *(uint2*)&H[(size_t)gr * 128 + tx * 4] = q0;
            *(uint2*)&H[(size_t)gr * 128 + 64 + tx * 4] = q1;
        }
    }
}

// ---------------- MFMA GEMM (layers 2,3): H = half((Xh @ W) * dscale[row]) ----------------
// 256 threads = 4 waves, 16 rows/wave (64 rows/block).  No LDS: A frags 16B/lane from Xh,
// B frags from pre-swizzled wfrag (lane-indexed -> coalesced 1KB loads, L2-broadcast).
// mfma_f32_16x16x32_f16, fp32 accumulation.  Layouts:
//   A[m=lane&15][k=quad*8+j], B[k=quad*8+j][n=lane&15], D: col=lane&15, row=quad*4+reg.
__global__ __launch_bounds__(256) void gemm_mfma(const __half* __restrict__ Xh,
                                                 const __half* __restrict__ wfrag,
                                                 const float* __restrict__ dscale,
                                                 __half* __restrict__ H, int Nrows) {
    int l = threadIdx.x & 63;
    int wid = threadIdx.x >> 6;
    int rowbase = blockIdx.x * 64 + wid * 16;
    int quad = l >> 4;
    int n = l & 15;
    int ra = rowbase + (l & 15);
    if (ra > Nrows - 1) ra = Nrows - 1;
    const v8h* Xf = (const v8h*)(Xh + (size_t)ra * 128);   // frag (s,quad) at index s*4+quad
    v8h a0 = Xf[0 * 4 + quad];
    v8h a1 = Xf[1 * 4 + quad];
    v8h a2 = Xf[2 * 4 + quad];
    v8h a3 = Xf[3 * 4 + quad];
    const v8h* Wf = (const v8h*)wfrag;
    v4f acc[8] = {};
#pragma unroll
    for (int c = 0; c < 8; ++c) {
        v8h b0 = Wf[(c * 4 + 0) * 64 + l];
        v8h b1 = Wf[(c * 4 + 1) * 64 + l];
        v8h b2 = Wf[(c * 4 + 2) * 64 + l];
        v8h b3 = Wf[(c * 4 + 3) * 64 + l];
        acc[c] = __builtin_amdgcn_mfma_f32_16x16x32_f16(a0, b0, acc[c], 0, 0, 0);
        acc[c] = __builtin_amdgcn_mfma_f32_16x16x32_f16(a1, b1, acc[c], 0, 0, 0);
        acc[c] = __builtin_amdgcn_mfma_f32_16x16x32_f16(a2, b2, acc[c], 0, 0, 0);
        acc[c] = __builtin_amdgcn_mfma_f32_16x16x32_f16(a3, b3, acc[c], 0, 0, 0);
    }
#pragma unroll
    for (int reg = 0; reg < 4; ++reg) {
        int gr = rowbase + quad * 4 + reg;
        if (gr < Nrows) {
            float s = dscale[gr];
#pragma unroll
            for (int c = 0; c < 8; ++c)
                H[(size_t)gr * 128 + c * 16 + n] = __float2half_rn(acc[c][reg] * s);
        }
    }
}

// ---------------- scanA: per-block inclusive scan of (cnt[i]+1) ----------------
__global__ void scanA(const int* __restrict__ cnt, int* __restrict__ tmp,
                      int* __restrict__ bsum, int n) {
    __shared__ int s[256];
    int i = blockIdx.x * 256 + threadIdx.x;
    int v = (i < n) ? (cnt[i] + 1) : 0;
    s[threadIdx.x] = v;
    __syncthreads();
    for (int off = 1; off < 256; off <<= 1) {
        int x = (threadIdx.x >= off) ? s[threadIdx.x - off] : 0;
        __syncthreads();
        s[threadIdx.x] += x;
        __syncthreads();
    }
    if (i < n) tmp[i] = s[threadIdx.x];
    if (threadIdx.x == 255) bsum[blockIdx.x] = s[255];
}

// ---------------- scanB: redundant partial-scan + apply + dinv + self-loop ----------------
__global__ void scanB(const int* __restrict__ tmp, const int* __restrict__ bsum,
                      const int* __restrict__ cnt, int* __restrict__ rowptr,
                      float* __restrict__ dinv, int* __restrict__ col, int n, int nb) {
    __shared__ int p[256];
    int t = threadIdx.x;
    p[t] = (t < nb) ? bsum[t] : 0;
    __syncthreads();
    for (int off = 1; off < 256; off <<= 1) {
        int x = (t >= off) ? p[t - off] : 0;
        __syncthreads();
        p[t] += x;
        __syncthreads();
    }
    int prefix = (blockIdx.x == 0) ? 0 : p[blockIdx.x - 1];
    int i = blockIdx.x * 256 + t;
    if (i < n) {
        int inc = tmp[i] + prefix;             // inclusive scan of (cnt+1)
        rowptr[i + 1] = inc;
        int c1 = cnt[i] + 1;
        dinv[i] = rsqrtf((float)c1);
        col[inc - c1] = i;                     // self-loop occupies slot 0 of row i
        if (i == 0) rowptr[0] = 0;
    }
}

// ---------------- atomic-free CSR fill: col[rowptr[d]+1+rank[e]] = src[e] ----------------
__global__ __launch_bounds__(256) void fill4(const int* __restrict__ src,
                                             const int* __restrict__ dst,
                                             const int* __restrict__ rank,
                                             const int* __restrict__ rowptr,
                                             int* __restrict__ col, int E) {
    int base = blockIdx.x * 1024 + threadIdx.x * 4;
    if (base + 3 < E) {
        int d0 = dst[base], d1 = dst[base + 1], d2 = dst[base + 2], d3 = dst[base + 3];
        int s0 = src[base], s1 = src[base + 1], s2 = src[base + 2], s3 = src[base + 3];
        int r0 = rank[base], r1 = rank[base + 1], r2 = rank[base + 2], r3 = rank[base + 3];
        col[rowptr[d0] + 1 + r0] = s0;
        col[rowptr[d1] + 1 + r1] = s1;
        col[rowptr[d2] + 1 + r2] = s2;
        col[rowptr[d3] + 1 + r3] = s3;
    } else {
        for (int e = base; e < E; ++e)
            col[rowptr[dst[e]] + 1 + rank[e]] = src[e];
    }
}

// ---------------- CSR aggregation over fp16 H -> fp16 out, unroll-8 ----------------
__global__ __launch_bounds__(256) void agg_h(const __half* __restrict__ H,
                                             const float* __restrict__ dinv,
                                             const int* __restrict__ rowptr,
                                             const int* __restrict__ col,
                                             const float* __restrict__ bias,
                                             __half* __restrict__ out,
                                             int n, int relu, int gdinv) {
    int node = blockIdx.x * 16 + (threadIdx.x >> 4);
    int t = (threadIdx.x & 15) * 8;       // dim offset (halfs)
    if (node >= n) return;
    int beg = rowptr[node], end = rowptr[node + 1];
    float a[8] = {};
    int k = beg;
    for (; k + 8 <= end; k += 8) {
        int s[8];
#pragma unroll
        for (int j = 0; j < 8; ++j) s[j] = col[k + j];
        uint4 r[8];
#pragma unroll
        for (int j = 0; j < 8; ++j) r[j] = *(const uint4*)&H[(size_t)s[j] * 128 + t];
        float w[8];
#pragma unroll
        for (int j = 0; j < 8; ++j) w[j] = gdinv ? dinv[s[j]] : 1.f;
#pragma unroll
        for (int j = 0; j < 8; ++j) {
            const __half2* h = (const __half2*)&r[j];
#pragma unroll
            for (int m = 0; m < 4; ++m) {
                float2 f = __half22float2(h[m]);
                a[2 * m] += f.x * w[j];
                a[2 * m + 1] += f.y * w[j];
            }
        }
    }
    for (; k + 4 <= end; k += 4) {
        int s0 = col[k], s1 = col[k + 1], s2 = col[k + 2], s3 = col[k + 3];
        float w0 = 1.f, w1 = 1.f, w2 = 1.f, w3 = 1.f;
        if (gdinv) { w0 = dinv[s0]; w1 = dinv[s1]; w2 = dinv[s2]; w3 = dinv[s3]; }
        uint4 r0 = *(const uint4*)&H[(size_t)s0 * 128 + t];
        uint4 r1 = *(const uint4*)&H[(size_t)s1 * 128 + t];
        uint4 r2 = *(const uint4*)&H[(size_t)s2 * 128 + t];
        uint4 r3 = *(const uint4*)&H[(size_t)s3 * 128 + t];
        const __half2* h0 = (const __half2*)&r0;
        const __half2* h1 = (const __half2*)&r1;
        const __half2* h2 = (const __half2*)&r2;
        const __half2* h3 = (const __half2*)&r3;
#pragma unroll
        for (int m = 0; m < 4; ++m) {
            float2 f0 = __half22float2(h0[m]);
            float2 f1 = __half22float2(h1[m]);
            float2 f2 = __half22float2(h2[m]);
            float2 f3 = __half22float2(h3[m]);
            a[2 * m]     += f0.x * w0 + f1.x * w1 + f2.x * w2 + f3.x * w3;
            a[2 * m + 1] += f0.y * w0 + f1.y * w1 + f2.y * w2 + f3.y * w3;
        }
    }
    for (; k < end; ++k) {
        int s0 = col[k];
        float w0 = gdinv ? dinv[s0] : 1.f;
        uint4 r0 = *(const uint4*)&H[(size_t)s0 * 128 + t];
        const __half2* h0 = (const __half2*)&r0;
#pragma unroll
        for (int m = 0; m < 4; ++m) {
            float2 f0 = __half22float2(h0[m]);
            a[2 * m] += f0.x * w0;
            a[2 * m + 1] += f0.y * w0;
        }
    }
    float dn = dinv[node];
    float4 b0 = *(const float4*)&bias[t];
    float4 b1 = *(const float4*)&bias[t + 4];
    float r0 = a[0] * dn + b0.x, r1 = a[1] * dn + b0.y;
    float r2 = a[2] * dn + b0.z, r3 = a[3] * dn + b0.w;
    float r4 = a[4] * dn + b1.x, r5 = a[5] * dn + b1.y;
    float r6 = a[6] * dn + b1.z, r7 = a[7] * dn + b1.w;
    if (relu) {
        r0 = fmaxf(r0, 0.f); r1 = fmaxf(r1, 0.f); r2 = fmaxf(r2, 0.f); r3 = fmaxf(r3, 0.f);
        r4 = fmaxf(r4, 0.f); r5 = fmaxf(r5, 0.f); r6 = fmaxf(r6, 0.f); r7 = fmaxf(r7, 0.f);
    }
    auto pk = [](float x, float y) { __half2 h = __floats2half2_rn(x, y); return *(unsigned int*)&h; };
    uint4 o = make_uint4(pk(r0, r1), pk(r2, r3), pk(r4, r5), pk(r6, r7));
    *(uint4*)&out[(size_t)node * 128 + t] = o;
}

// ---------------- edge decoder over fp16 X: out[e] = dot(X[u], X[v]) ----------------
__global__ __launch_bounds__(256) void decoder_h(const __half* __restrict__ X,
                                                 const int* __restrict__ eli,
                                                 float* __restrict__ out, int EL) {
    int e = blockIdx.x * 16 + (threadIdx.x >> 4);
    int lane = threadIdx.x & 15;
    if (e >= EL) return;
    int u = eli[e], v = eli[EL + e];
    uint4 ra = *(const uint4*)&X[(size_t)u * 128 + lane * 8];
    uint4 rb = *(const uint4*)&X[(size_t)v * 128 + lane * 8];
    const __half2* ha = (const __half2*)&ra;
    const __half2* hb = (const __half2*)&rb;
    float d = 0.f;
#pragma unroll
    for (int j = 0; j < 4; ++j) {
        float2 fa = __half22float2(ha[j]);
        float2 fb = __half22float2(hb[j]);
        d += fa.x * fb.x + fa.y * fb.y;
    }
#pragma unroll
    for (int off = 8; off > 0; off >>= 1) d += __shfl_xor(d, off);
    if (lane == 0) out[e] = d;
}

extern "C" void kernel_launch(void* const* d_in, const int* in_sizes, int n_in,
                              void* d_out, int out_size, void* d_ws, size_t ws_size,
                              hipStream_t stream) {
    const float* x0 = (const float*)d_in[0];
    const float* W1 = (const float*)d_in[1];
    const float* b1 = (const float*)d_in[2];
    const float* W2 = (const float*)d_in[3];
    const float* b2 = (const float*)d_in[4];
    const float* W3 = (const float*)d_in[5];
    const float* b3 = (const float*)d_in[6];
    const int* ei   = (const int*)d_in[7];
    const int* eli  = (const int*)d_in[8];
    float* out = (float*)d_out;

    const int D = 128;
    const int N  = in_sizes[0] / D;
    const int E  = in_sizes[7] / 2;
    const int EL = in_sizes[8] / 2;

    const int* src = ei;        // edge_index[0]
    const int* dst = ei + E;    // edge_index[1]

    // -------- workspace carve-up (256B aligned) --------
    char* ws = (char*)d_ws;
    size_t off = 0;
    auto alloc = [&](size_t bytes) -> void* {
        off = (off + 255) & ~(size_t)255;
        void* p = ws + off;
        off += bytes;
        return p;
    };
    int*    cnt    = (int*)alloc((size_t)N * sizeof(int));
    int*    tmp    = (int*)alloc((size_t)N * sizeof(int));
    int*    bsum   = (int*)alloc(256 * sizeof(int));
    int*    rowptr = (int*)alloc((size_t)(N + 1) * sizeof(int));
    float*  dinv   = (float*)alloc((size_t)N * sizeof(float));
    int*    rank   = (int*)alloc((size_t)E * sizeof(int));
    int*    col    = (int*)alloc((size_t)(E + N) * sizeof(int));
    __half* wfrag  = (__half*)alloc((size_t)2 * 16384 * sizeof(__half));  // W2,W3 frag-order
    __half* hbuf   = (__half*)alloc((size_t)N * D * sizeof(__half));  // gemm out
    __half* xbuf   = (__half*)alloc((size_t)N * D * sizeof(__half));  // agg out
    (void)ws_size;

    // zero the degree counters
    hipMemsetAsync(cnt, 0, (size_t)N * sizeof(int), stream);

    int nbN = (N + 255) / 256;
    int nbE4 = (E + 1023) / 1024;
    int gemmGrid = (N + 127) / 128;       // layer-1 VALU gemm (128-row tiles)
    int mfmaGrid = (N + 63) / 64;         // MFMA gemm (64-row blocks)
    int aggGrid  = (N + 15) / 16;

    // ---- FUSED: layer-1 GEMM (first) + degree/rank atomic pass + W2/W3 swizzle ----
    gemm1_deg<<<gemmGrid + nbE4 + 128, 256, 0, stream>>>(x0, W1, hbuf, N,
                                                         gemmGrid, nbE4,
                                                         dst, cnt, rank, E,
                                                         W2, W3, wfrag);

    // ---- scan (2 dispatches) -> rowptr/dinv/self-loops ----
    scanA<<<nbN, 256, 0, stream>>>(cnt, tmp, bsum, N);
    scanB<<<nbN, 256, 0, stream>>>(tmp, bsum, cnt, rowptr, dinv, col, N, nbN);
    // ---- atomic-free CSR fill ----
    fill4<<<nbE4, 256, 0, stream>>>(src, dst, rank, rowptr, col, E);

    // ---- layer 1: agg gathers dinv[s] per edge (H1 unscaled) ----
    agg_h<<<aggGrid, 256, 0, stream>>>(hbuf, dinv, rowptr, col, b1, xbuf, N, 1, 1);
    // ---- layer 2 (MFMA) ----
    gemm_mfma<<<mfmaGrid, 256, 0, stream>>>(xbuf, wfrag, dinv, hbuf, N);
    agg_h<<<aggGrid, 256, 0, stream>>>(hbuf, dinv, rowptr, col, b2, xbuf, N, 1, 0);
    // ---- layer 3 (MFMA) ----
    gemm_mfma<<<mfmaGrid, 256, 0, stream>>>(xbuf, wfrag + 16384, dinv, hbuf, N);
    agg_h<<<aggGrid, 256, 0, stream>>>(hbuf, dinv, rowptr, col, b3, xbuf, N, 0, 0);

    // ---- decoder ----
    decoder_h<<<(EL + 15) / 16, 256, 0, stream>>>(xbuf, eli, out, EL);
}

// Round 15
// 271.317 us; speedup vs baseline: 1.3524x; 1.0615x over previous
//
#include <hip/hip_runtime.h>
#include <hip/hip_bf16.h>
#include <hip/hip_fp16.h>

typedef _Float16 v8h __attribute__((ext_vector_type(8)));
typedef float v4f __attribute__((ext_vector_type(4)));

// ---------------- FUSED: layer-1 GEMM + degree/rank atomic pass + W2/W3 frag-swizzle ----------------
// Blocks [0, gemmBlocks): H1 = half(x0 @ W1), UNSCALED (dinv applied per-edge in agg L1).
// Blocks [gemmBlocks, +degBlocks): rank[e] = atomicAdd(&cnt[dst[e]],1), 4 edges/thread.
// Blocks [gemmBlocks+degBlocks, +128): repack W2,W3 (fp32) into fp16 MFMA B-fragment order.
__global__ __launch_bounds__(256) void gemm1_deg(const float* __restrict__ X,
                                                 const float* __restrict__ W,
                                                 __half* __restrict__ H, int Nrows,
                                                 int gemmBlocks, int degBlocks,
                                                 const int* __restrict__ dst,
                                                 int* __restrict__ cnt,
                                                 int* __restrict__ rank, int E,
                                                 const float* __restrict__ W2,
                                                 const float* __restrict__ W3,
                                                 __half* __restrict__ wfrag) {
    int tid = threadIdx.x;
    if (blockIdx.x >= gemmBlocks + degBlocks) {
        int o = (blockIdx.x - gemmBlocks - degBlocks) * 256 + tid;
        int w = o >> 14, r = o & 16383;
        const float* Ws = w ? W3 : W2;
        int k = r >> 7, ncol = r & 127;
        int c = ncol >> 4, nl = ncol & 15;
        int s = k >> 5, quad = (k >> 3) & 3, j = k & 7;
        int di = ((c * 4 + s) * 64 + quad * 16 + nl) * 8 + j;
        wfrag[(size_t)w * 16384 + di] = __float2half_rn(Ws[r]);
        return;
    }
    if (blockIdx.x >= gemmBlocks) {
        int base = (blockIdx.x - gemmBlocks) * 1024 + tid * 4;
        if (base + 3 < E) {
            int d0 = dst[base], d1 = dst[base + 1], d2 = dst[base + 2], d3 = dst[base + 3];
            int r0 = atomicAdd(&cnt[d0], 1);
            int r1 = atomicAdd(&cnt[d1], 1);
            int r2 = atomicAdd(&cnt[d2], 1);
            int r3 = atomicAdd(&cnt[d3], 1);
            rank[base] = r0; rank[base + 1] = r1; rank[base + 2] = r2; rank[base + 3] = r3;
        } else {
            for (int e = base; e < E; ++e) rank[e] = atomicAdd(&cnt[dst[e]], 1);
        }
        return;
    }
    __shared__ __align__(16) float xs[16][132];
    __shared__ __align__(16) float ws[16][128];
    int tx = tid & 15;
    int ty = tid >> 4;
    int row0 = blockIdx.x * 128;
    float acc[8][8] = {};
    for (int k0 = 0; k0 < 128; k0 += 16) {
        {
            int r = tid >> 2;
            int j = (tid & 3) * 4;
            int gr = row0 + r;
            float4 v = (gr < Nrows) ? *(const float4*)&X[(size_t)gr * 128 + k0 + j]
                                    : make_float4(0.f, 0.f, 0.f, 0.f);
            xs[j + 0][r] = v.x; xs[j + 1][r] = v.y; xs[j + 2][r] = v.z; xs[j + 3][r] = v.w;
            int gr2 = gr + 64;
            float4 u = (gr2 < Nrows) ? *(const float4*)&X[(size_t)gr2 * 128 + k0 + j]
                                     : make_float4(0.f, 0.f, 0.f, 0.f);
            xs[j + 0][r + 64] = u.x; xs[j + 1][r + 64] = u.y;
            xs[j + 2][r + 64] = u.z; xs[j + 3][r + 64] = u.w;
        }
        {
            const float4* Wv = (const float4*)&W[(size_t)k0 * 128];
            float4* wsv = (float4*)&ws[0][0];
            wsv[tid] = Wv[tid];
            wsv[tid + 256] = Wv[tid + 256];
        }
        __syncthreads();
#pragma unroll
        for (int kk = 0; kk < 16; ++kk) {
            float4 xa = *(float4*)&xs[kk][ty * 4];
            float4 xb = *(float4*)&xs[kk][ty * 4 + 64];
            float4 wa = *(float4*)&ws[kk][tx * 4];
            float4 wb = *(float4*)&ws[kk][tx * 4 + 64];
            float xr[8] = {xa.x, xa.y, xa.z, xa.w, xb.x, xb.y, xb.z, xb.w};
            float wr[8] = {wa.x, wa.y, wa.z, wa.w, wb.x, wb.y, wb.z, wb.w};
#pragma unroll
            for (int i = 0; i < 8; ++i)
#pragma unroll
                for (int j = 0; j < 8; ++j)
                    acc[i][j] += xr[i] * wr[j];
        }
        __syncthreads();
    }
    auto pk = [](float x, float y) { __half2 h = __floats2half2_rn(x, y); return *(unsigned int*)&h; };
#pragma unroll
    for (int i = 0; i < 8; ++i) {
        int gr = row0 + ((i < 4) ? (ty * 4 + i) : (64 + ty * 4 + i - 4));
        if (gr < Nrows) {
            uint2 q0 = make_uint2(pk(acc[i][0], acc[i][1]), pk(acc[i][2], acc[i][3]));
            uint2 q1 = make_uint2(pk(acc[i][4], acc[i][5]), pk(acc[i][6], acc[i][7]));
            *(uint2*)&H[(size_t)gr * 128 + tx * 4] = q0;
            *(uint2*)&H[(size_t)gr * 128 + 64 + tx * 4] = q1;
        }
    }
}

// ---------------- FUSED layer (2,3): Out = post( (dinv ⊙ Â·Xs) @ W + b ) ----------------
// Aggregate-first (A(XW)=(AX)W).  Block = 64 rows.  Phase A: 4 passes x (16 nodes x
// 16 lanes) gather y = dinv_n * Σ x̃_s (x̃ pre-scaled) into 17KB LDS tile (fp16).
// Phase B: per-wave 16-row MFMA vs pre-swizzled wfrag (no LDS for W, coalesced 1KB loads).
// finalLayer=0: out = dinv ⊙ relu(z) (next x̃);  =1: out = z (decoder input).
__global__ __launch_bounds__(256) void agg_gemm(const __half* __restrict__ Xs,
                                                const float* __restrict__ dinv,
                                                const int* __restrict__ rowptr,
                                                const int* __restrict__ col,
                                                const __half* __restrict__ wfrag,
                                                const float* __restrict__ bias,
                                                __half* __restrict__ Out,
                                                int n, int finalLayer) {
    __shared__ __align__(16) _Float16 y[64][136];   // +8 halfs pad: col-reads 2-way (free)
    int tid = threadIdx.x;
    int rowbase = blockIdx.x * 64;
    // ---- phase A ----
    {
        int sub = tid >> 4;               // node-in-group 0..15
        int t = (tid & 15) * 8;           // dim offset (halfs)
        for (int g = 0; g < 4; ++g) {
            int rr = g * 16 + sub;
            int node = rowbase + rr;
            float a[8] = {};
            if (node < n) {
                int beg = rowptr[node], end = rowptr[node + 1];
                int k = beg;
                for (; k + 4 <= end; k += 4) {
                    int s0 = col[k], s1 = col[k + 1], s2 = col[k + 2], s3 = col[k + 3];
                    uint4 r0 = *(const uint4*)&Xs[(size_t)s0 * 128 + t];
                    uint4 r1 = *(const uint4*)&Xs[(size_t)s1 * 128 + t];
                    uint4 r2 = *(const uint4*)&Xs[(size_t)s2 * 128 + t];
                    uint4 r3 = *(const uint4*)&Xs[(size_t)s3 * 128 + t];
                    const __half2* h0 = (const __half2*)&r0;
                    const __half2* h1 = (const __half2*)&r1;
                    const __half2* h2 = (const __half2*)&r2;
                    const __half2* h3 = (const __half2*)&r3;
#pragma unroll
                    for (int m = 0; m < 4; ++m) {
                        float2 f0 = __half22float2(h0[m]);
                        float2 f1 = __half22float2(h1[m]);
                        float2 f2 = __half22float2(h2[m]);
                        float2 f3 = __half22float2(h3[m]);
                        a[2 * m]     += (f0.x + f1.x) + (f2.x + f3.x);
                        a[2 * m + 1] += (f0.y + f1.y) + (f2.y + f3.y);
                    }
                }
                for (; k < end; ++k) {
                    uint4 r0 = *(const uint4*)&Xs[(size_t)col[k] * 128 + t];
                    const __half2* h0 = (const __half2*)&r0;
#pragma unroll
                    for (int m = 0; m < 4; ++m) {
                        float2 f0 = __half22float2(h0[m]);
                        a[2 * m] += f0.x;
                        a[2 * m + 1] += f0.y;
                    }
                }
                float dn = dinv[node];
#pragma unroll
                for (int m = 0; m < 8; ++m) a[m] *= dn;
            }
            v8h yv;
#pragma unroll
            for (int m = 0; m < 8; ++m) yv[m] = (_Float16)a[m];
            *(v8h*)&y[rr][t] = yv;
        }
    }
    __syncthreads();
    // ---- phase B: 4 waves x 16 rows, mfma_f32_16x16x32_f16 ----
    int l = tid & 63;
    int wid = tid >> 6;
    int rb = wid * 16;
    int quad = l >> 4;
    int nn = l & 15;
    v8h a0 = *(const v8h*)&y[rb + nn][0 * 32 + quad * 8];
    v8h a1 = *(const v8h*)&y[rb + nn][1 * 32 + quad * 8];
    v8h a2 = *(const v8h*)&y[rb + nn][2 * 32 + quad * 8];
    v8h a3 = *(const v8h*)&y[rb + nn][3 * 32 + quad * 8];
    const v8h* Wf = (const v8h*)wfrag;
    v4f acc[8] = {};
#pragma unroll
    for (int c = 0; c < 8; ++c) {
        v8h b0 = Wf[(c * 4 + 0) * 64 + l];
        v8h b1 = Wf[(c * 4 + 1) * 64 + l];
        v8h b2 = Wf[(c * 4 + 2) * 64 + l];
        v8h b3 = Wf[(c * 4 + 3) * 64 + l];
        acc[c] = __builtin_amdgcn_mfma_f32_16x16x32_f16(a0, b0, acc[c], 0, 0, 0);
        acc[c] = __builtin_amdgcn_mfma_f32_16x16x32_f16(a1, b1, acc[c], 0, 0, 0);
        acc[c] = __builtin_amdgcn_mfma_f32_16x16x32_f16(a2, b2, acc[c], 0, 0, 0);
        acc[c] = __builtin_amdgcn_mfma_f32_16x16x32_f16(a3, b3, acc[c], 0, 0, 0);
    }
#pragma unroll
    for (int reg = 0; reg < 4; ++reg) {
        int gr = rowbase + rb + quad * 4 + reg;
        if (gr < n) {
            float dn = dinv[gr];
#pragma unroll
            for (int c = 0; c < 8; ++c) {
                float z = acc[c][reg] + bias[c * 16 + nn];
                if (!finalLayer) z = fmaxf(z, 0.f) * dn;
                Out[(size_t)gr * 128 + c * 16 + nn] = __float2half_rn(z);
            }
        }
    }
}

// ---------------- scanA: per-block inclusive scan of (cnt[i]+1) ----------------
__global__ void scanA(const int* __restrict__ cnt, int* __restrict__ tmp,
                      int* __restrict__ bsum, int n) {
    __shared__ int s[256];
    int i = blockIdx.x * 256 + threadIdx.x;
    int v = (i < n) ? (cnt[i] + 1) : 0;
    s[threadIdx.x] = v;
    __syncthreads();
    for (int off = 1; off < 256; off <<= 1) {
        int x = (threadIdx.x >= off) ? s[threadIdx.x - off] : 0;
        __syncthreads();
        s[threadIdx.x] += x;
        __syncthreads();
    }
    if (i < n) tmp[i] = s[threadIdx.x];
    if (threadIdx.x == 255) bsum[blockIdx.x] = s[255];
}

// ---------------- scanB: redundant partial-scan + apply + dinv + self-loop ----------------
__global__ void scanB(const int* __restrict__ tmp, const int* __restrict__ bsum,
                      const int* __restrict__ cnt, int* __restrict__ rowptr,
                      float* __restrict__ dinv, int* __restrict__ col, int n, int nb) {
    __shared__ int p[256];
    int t = threadIdx.x;
    p[t] = (t < nb) ? bsum[t] : 0;
    __syncthreads();
    for (int off = 1; off < 256; off <<= 1) {
        int x = (t >= off) ? p[t - off] : 0;
        __syncthreads();
        p[t] += x;
        __syncthreads();
    }
    int prefix = (blockIdx.x == 0) ? 0 : p[blockIdx.x - 1];
    int i = blockIdx.x * 256 + t;
    if (i < n) {
        int inc = tmp[i] + prefix;
        rowptr[i + 1] = inc;
        int c1 = cnt[i] + 1;
        dinv[i] = rsqrtf((float)c1);
        col[inc - c1] = i;
        if (i == 0) rowptr[0] = 0;
    }
}

// ---------------- atomic-free CSR fill ----------------
__global__ __launch_bounds__(256) void fill4(const int* __restrict__ src,
                                             const int* __restrict__ dst,
                                             const int* __restrict__ rank,
                                             const int* __restrict__ rowptr,
                                             int* __restrict__ col, int E) {
    int base = blockIdx.x * 1024 + threadIdx.x * 4;
    if (base + 3 < E) {
        int d0 = dst[base], d1 = dst[base + 1], d2 = dst[base + 2], d3 = dst[base + 3];
        int s0 = src[base], s1 = src[base + 1], s2 = src[base + 2], s3 = src[base + 3];
        int r0 = rank[base], r1 = rank[base + 1], r2 = rank[base + 2], r3 = rank[base + 3];
        col[rowptr[d0] + 1 + r0] = s0;
        col[rowptr[d1] + 1 + r1] = s1;
        col[rowptr[d2] + 1 + r2] = s2;
        col[rowptr[d3] + 1 + r3] = s3;
    } else {
        for (int e = base; e < E; ++e)
            col[rowptr[dst[e]] + 1 + rank[e]] = src[e];
    }
}

// ---------------- layer-1 aggregation: x̃1 = dinv ⊙ relu(dinv_n·Σ dinv_s·H1[s] + b) ----------------
__global__ __launch_bounds__(256) void agg_h(const __half* __restrict__ H,
                                             const float* __restrict__ dinv,
                                             const int* __restrict__ rowptr,
                                             const int* __restrict__ col,
                                             const float* __restrict__ bias,
                                             __half* __restrict__ out, int n) {
    int node = blockIdx.x * 16 + (threadIdx.x >> 4);
    int t = (threadIdx.x & 15) * 8;
    if (node >= n) return;
    int beg = rowptr[node], end = rowptr[node + 1];
    float a[8] = {};
    int k = beg;
    for (; k + 4 <= end; k += 4) {
        int s0 = col[k], s1 = col[k + 1], s2 = col[k + 2], s3 = col[k + 3];
        float w0 = dinv[s0], w1 = dinv[s1], w2 = dinv[s2], w3 = dinv[s3];
        uint4 r0 = *(const uint4*)&H[(size_t)s0 * 128 + t];
        uint4 r1 = *(const uint4*)&H[(size_t)s1 * 128 + t];
        uint4 r2 = *(const uint4*)&H[(size_t)s2 * 128 + t];
        uint4 r3 = *(const uint4*)&H[(size_t)s3 * 128 + t];
        const __half2* h0 = (const __half2*)&r0;
        const __half2* h1 = (const __half2*)&r1;
        const __half2* h2 = (const __half2*)&r2;
        const __half2* h3 = (const __half2*)&r3;
#pragma unroll
        for (int m = 0; m < 4; ++m) {
            float2 f0 = __half22float2(h0[m]);
            float2 f1 = __half22float2(h1[m]);
            float2 f2 = __half22float2(h2[m]);
            float2 f3 = __half22float2(h3[m]);
            a[2 * m]     += f0.x * w0 + f1.x * w1 + f2.x * w2 + f3.x * w3;
            a[2 * m + 1] += f0.y * w0 + f1.y * w1 + f2.y * w2 + f3.y * w3;
        }
    }
    for (; k < end; ++k) {
        int s0 = col[k];
        float w0 = dinv[s0];
        uint4 r0 = *(const uint4*)&H[(size_t)s0 * 128 + t];
        const __half2* h0 = (const __half2*)&r0;
#pragma unroll
        for (int m = 0; m < 4; ++m) {
            float2 f0 = __half22float2(h0[m]);
            a[2 * m] += f0.x * w0;
            a[2 * m + 1] += f0.y * w0;
        }
    }
    float dn = dinv[node];
    float4 b0 = *(const float4*)&bias[t];
    float4 b1 = *(const float4*)&bias[t + 4];
    float r0 = fmaxf(a[0] * dn + b0.x, 0.f) * dn;
    float r1 = fmaxf(a[1] * dn + b0.y, 0.f) * dn;
    float r2 = fmaxf(a[2] * dn + b0.z, 0.f) * dn;
    float r3 = fmaxf(a[3] * dn + b0.w, 0.f) * dn;
    float r4 = fmaxf(a[4] * dn + b1.x, 0.f) * dn;
    float r5 = fmaxf(a[5] * dn + b1.y, 0.f) * dn;
    float r6 = fmaxf(a[6] * dn + b1.z, 0.f) * dn;
    float r7 = fmaxf(a[7] * dn + b1.w, 0.f) * dn;
    auto pk = [](float x, float y) { __half2 h = __floats2half2_rn(x, y); return *(unsigned int*)&h; };
    uint4 o = make_uint4(pk(r0, r1), pk(r2, r3), pk(r4, r5), pk(r6, r7));
    *(uint4*)&out[(size_t)node * 128 + t] = o;
}

// ---------------- edge decoder over fp16 X ----------------
__global__ __launch_bounds__(256) void decoder_h(const __half* __restrict__ X,
                                                 const int* __restrict__ eli,
                                                 float* __restrict__ out, int EL) {
    int e = blockIdx.x * 16 + (threadIdx.x >> 4);
    int lane = threadIdx.x & 15;
    if (e >= EL) return;
    int u = eli[e], v = eli[EL + e];
    uint4 ra = *(const uint4*)&X[(size_t)u * 128 + lane * 8];
    uint4 rb = *(const uint4*)&X[(size_t)v * 128 + lane * 8];
    const __half2* ha = (const __half2*)&ra;
    const __half2* hb = (const __half2*)&rb;
    float d = 0.f;
#pragma unroll
    for (int j = 0; j < 4; ++j) {
        float2 fa = __half22float2(ha[j]);
        float2 fb = __half22float2(hb[j]);
        d += fa.x * fb.x + fa.y * fb.y;
    }
#pragma unroll
    for (int off = 8; off > 0; off >>= 1) d += __shfl_xor(d, off);
    if (lane == 0) out[e] = d;
}

extern "C" void kernel_launch(void* const* d_in, const int* in_sizes, int n_in,
                              void* d_out, int out_size, void* d_ws, size_t ws_size,
                              hipStream_t stream) {
    const float* x0 = (const float*)d_in[0];
    const float* W1 = (const float*)d_in[1];
    const float* b1 = (const float*)d_in[2];
    const float* W2 = (const float*)d_in[3];
    const float* b2 = (const float*)d_in[4];
    const float* W3 = (const float*)d_in[5];
    const float* b3 = (const float*)d_in[6];
    const int* ei   = (const int*)d_in[7];
    const int* eli  = (const int*)d_in[8];
    float* out = (float*)d_out;

    const int D = 128;
    const int N  = in_sizes[0] / D;
    const int E  = in_sizes[7] / 2;
    const int EL = in_sizes[8] / 2;

    const int* src = ei;
    const int* dst = ei + E;

    // -------- workspace carve-up (256B aligned) --------
    char* ws = (char*)d_ws;
    size_t off = 0;
    auto alloc = [&](size_t bytes) -> void* {
        off = (off + 255) & ~(size_t)255;
        void* p = ws + off;
        off += bytes;
        return p;
    };
    int*    cnt    = (int*)alloc((size_t)N * sizeof(int));
    int*    tmp    = (int*)alloc((size_t)N * sizeof(int));
    int*    bsum   = (int*)alloc(256 * sizeof(int));
    int*    rowptr = (int*)alloc((size_t)(N + 1) * sizeof(int));
    float*  dinv   = (float*)alloc((size_t)N * sizeof(float));
    int*    rank   = (int*)alloc((size_t)E * sizeof(int));
    int*    col    = (int*)alloc((size_t)(E + N) * sizeof(int));
    __half* wfrag  = (__half*)alloc((size_t)2 * 16384 * sizeof(__half));
    __half* hbuf   = (__half*)alloc((size_t)N * D * sizeof(__half));  // h1 / x̃2
    __half* xbuf   = (__half*)alloc((size_t)N * D * sizeof(__half));  // x̃1 / x3
    (void)ws_size;

    hipMemsetAsync(cnt, 0, (size_t)N * sizeof(int), stream);

    int nbN = (N + 255) / 256;
    int nbE4 = (E + 1023) / 1024;
    int gemmGrid = (N + 127) / 128;
    int fusedGrid = (N + 63) / 64;
    int aggGrid  = (N + 15) / 16;

    // ---- FUSED: layer-1 GEMM + degree/rank atomics + W2/W3 swizzle ----
    gemm1_deg<<<gemmGrid + nbE4 + 128, 256, 0, stream>>>(x0, W1, hbuf, N,
                                                         gemmGrid, nbE4,
                                                         dst, cnt, rank, E,
                                                         W2, W3, wfrag);

    // ---- scan -> rowptr/dinv/self-loops; atomic-free fill ----
    scanA<<<nbN, 256, 0, stream>>>(cnt, tmp, bsum, N);
    scanB<<<nbN, 256, 0, stream>>>(tmp, bsum, cnt, rowptr, dinv, col, N, nbN);
    fill4<<<nbE4, 256, 0, stream>>>(src, dst, rank, rowptr, col, E);

    // ---- layer 1: agg over unscaled h1, emits prescaled x̃1 ----
    agg_h<<<aggGrid, 256, 0, stream>>>(hbuf, dinv, rowptr, col, b1, xbuf, N);
    // ---- layer 2: fused aggregate-first + MFMA, emits prescaled x̃2 ----
    agg_gemm<<<fusedGrid, 256, 0, stream>>>(xbuf, dinv, rowptr, col, wfrag, b2, hbuf, N, 0);
    // ---- layer 3: fused, emits final x3 ----
    agg_gemm<<<fusedGrid, 256, 0, stream>>>(hbuf, dinv, rowptr, col, wfrag + 16384, b3, xbuf, N, 1);

    // ---- decoder ----
    decoder_h<<<(EL + 15) / 16, 256, 0, stream>>>(xbuf, eli, out, EL);
}